// Round 7
// baseline (591.034 us; speedup 1.0000x reference)
//
#include <hip/hip_runtime.h>

// ---------------------------------------------------------------------------
// DepTreeLSTM on MI355X — round 7: single tree-local fused kernel.
// 4 trees per block (512 thr, 8 waves), 1024 blocks, 7 phases inside one
// kernel separated by __syncthreads(): pre(emb@[Wiou|Wf]) -> leaf -> lvl1..5.
// All h/c/pre traffic is block-local (same-CU L2 hits). B matrices streamed
// per-ks via global_load_lds double-buffer (R5/R6 scheme, verbatim).
// ws: BW 0 | BU 256K | cbuf f32 @1MB | hbuf bf16 @+132MB | pre bf16 @+198MB.
// ---------------------------------------------------------------------------

typedef float f32x4 __attribute__((ext_vector_type(4)));
typedef __bf16 bf16x8 __attribute__((ext_vector_type(8)));
typedef unsigned short u16x8 __attribute__((ext_vector_type(8)));

__device__ __forceinline__ unsigned short f2bf(float x) {
  unsigned int u = __float_as_uint(x);
  return (unsigned short)((u + 0x7fffu + ((u >> 16) & 1u)) >> 16);
}
__device__ __forceinline__ float bf2f(unsigned short u) {
  return __uint_as_float(((unsigned int)u) << 16);
}
__device__ __forceinline__ float sigf(float x) { return 1.f / (1.f + __expf(-x)); }
__device__ __forceinline__ float tanhfast(float x) {
  return 1.f - 2.f / (__expf(2.f * x) + 1.f);
}
__device__ __forceinline__ void gld_lds16(const unsigned short* g, unsigned short* l) {
  __builtin_amdgcn_global_load_lds((const __attribute__((address_space(1))) void*)g,
                                   (__attribute__((address_space(3))) void*)l, 16, 0, 0);
}

#define ASTR 264  // A row-image stride in shorts (K=256 + 8 pad)

// Fragment pack (K=256): X[((T*8+ks)*64+lane)*8+j], lane=kq*16+cl,
// col=T*16+cl, k=ks*32+kq*8+j.
// BW (32 tiles, N=512): col<384: W_iou[k][col]; else W_f[k][col-384].
// BU (40 tiles, N=640): col<384: U_iou[k][col]; else U_f_w[k][col-384].
__global__ void prep_kernel(const float* __restrict__ Wi, const float* __restrict__ Ui,
                            const float* __restrict__ Wf, const float* __restrict__ Uf,
                            unsigned short* __restrict__ BW, unsigned short* __restrict__ BU) {
  int idx = blockIdx.x * 512 + threadIdx.x;  // 0 .. 294911
  if (idx < 131072) {
    int j = idx & 7, lane = (idx >> 3) & 63, ks = (idx >> 9) & 7, T = idx >> 12;
    int cl = lane & 15, kq = lane >> 4;
    int c = T * 16 + cl, k = ks * 32 + kq * 8 + j;
    BW[idx] = f2bf((c < 384) ? Wi[k * 384 + c] : Wf[k * 128 + (c - 384)]);
  } else {
    int i2 = idx - 131072;
    int j = i2 & 7, lane = (i2 >> 3) & 63, ks = (i2 >> 9) & 7, T = i2 >> 12;
    int cl = lane & 15, kq = lane >> 4;
    int c = T * 16 + cl, k = ks * 32 + kq * 8 + j;
    BU[i2] = f2bf((c < 384) ? Ui[k * 384 + c] : Uf[k * 256 + (c - 384)]);
  }
}

// double-buffered per-ks B DMA + MFMA loop; ends with __syncthreads()
template <int MT, int NT>
__device__ __forceinline__ void run_gemm(const unsigned short* __restrict__ Bsrc,
                                         unsigned short (*Bb)[40 * 512],
                                         const unsigned short* Ar,
                                         int lane, int w, f32x4 (&acc)[MT][NT]) {
  const int cl = lane & 15, kq = lane >> 4;
  int cur = 0;
  for (int ks = 0; ks < 8; ++ks) {
    if (ks < 7) {
#pragma unroll
      for (int c = 0; c < NT; ++c) {
        const int T = c * 8 + w;
        gld_lds16(&Bsrc[(size_t)(T * 8 + ks + 1) * 512 + lane * 8], &Bb[cur ^ 1][T * 512]);
      }
    }
    bf16x8 b[NT];
#pragma unroll
    for (int t = 0; t < NT; ++t)
      b[t] = *(const bf16x8*)&Bb[cur][(t * 8 + w) * 512 + lane * 8];
#pragma unroll
    for (int mt = 0; mt < MT; ++mt) {
      const bf16x8 a = *(const bf16x8*)&Ar[(mt * 16 + cl) * ASTR + ks * 32 + kq * 8];
#pragma unroll
      for (int t = 0; t < NT; ++t)
        acc[mt][t] = __builtin_amdgcn_mfma_f32_16x16x32_bf16(a, b[t], acc[mt][t], 0, 0, 0);
    }
    __syncthreads();
    cur ^= 1;
  }
}

// one tree level (d>=1). MT m-tiles (rows=MT*16, 4*cnt real), NT=5.
template <int MT>
__device__ __forceinline__ void do_level(
    int lcd, int offs, int g0,
    const float* __restrict__ cmask, const int* __restrict__ cidx,
    const int* __restrict__ ctype, const unsigned short* __restrict__ BU,
    const float* __restrict__ b_iou, const float* __restrict__ ufb,
    const float* __restrict__ bf_, const unsigned short* pre,
    float* hout, float* cbuf, unsigned short* hbuf,
    unsigned short* Ar, unsigned short (*Bb)[40 * 512],
    int tid, int lane, int w) {
  // DMA B slice ks=0 (overlaps A staging)
#pragma unroll
  for (int c = 0; c < 5; ++c) {
    const int T = c * 8 + w;
    gld_lds16(&BU[(size_t)(T * 8) * 512 + lane * 8], &Bb[0][T * 512]);
  }
  // stage A = [ht0 | ht1] for this level's rows (weighted child-h gather)
  {
    const int rblk = tid & 63, q = tid >> 6;
    if (rblk < MT * 16) {
      const int cnt = 1 << lcd;
      const int t = rblk >> lcd;
      const bool real = (t < 4);
      const int g = real ? (g0 + t * 63 + offs + (rblk & (cnt - 1))) : g0;
      const int ch0 = cidx[2 * g], ch1 = cidx[2 * g + 1];
      const int ty0 = ctype[2 * g], ty1 = ctype[2 * g + 1];
      const float c0 = real ? cmask[2 * g] : 0.f;
      const float c1 = real ? cmask[2 * g + 1] : 0.f;
      const int sel = q >> 2;  // 0: type-0 sum, 1: type-1 sum
      const float wA = (ty0 == sel) ? c0 : 0.f;
      const float wB = (ty1 == sel) ? c1 : 0.f;
      const int hc = (q & 3) * 32;
#pragma unroll
      for (int s = 0; s < 4; ++s) {
        const u16x8 va = *(const u16x8*)&hbuf[(size_t)ch0 * 128 + hc + 8 * s];
        const u16x8 vb = *(const u16x8*)&hbuf[(size_t)ch1 * 128 + hc + 8 * s];
        u16x8 o;
#pragma unroll
        for (int e = 0; e < 8; ++e) o[e] = f2bf(wA * bf2f(va[e]) + wB * bf2f(vb[e]));
        *(u16x8*)&Ar[rblk * ASTR + q * 32 + 8 * s] = o;
      }
    }
  }
  __syncthreads();

  f32x4 acc[MT][5];
#pragma unroll
  for (int mt = 0; mt < MT; ++mt)
#pragma unroll
    for (int t = 0; t < 5; ++t) acc[mt][t] = (f32x4){0.f, 0.f, 0.f, 0.f};
  run_gemm<MT, 5>(BU, Bb, Ar, lane, w, acc);

  // epilogue
  const int cl = lane & 15;
  const int rb = (lane >> 4) << 2;
  const int hcol = w * 16 + cl;
  const float bi = b_iou[hcol], bo = b_iou[128 + hcol], bu = b_iou[256 + hcol];
  const float f0b = ufb[hcol], f1b = ufb[128 + hcol], bfv = bf_[hcol];
  const int cnt = 1 << lcd;
#pragma unroll
  for (int mt = 0; mt < MT; ++mt) {
#pragma unroll
    for (int r = 0; r < 4; ++r) {
      const int row = (mt << 4) + rb + r;
      const int t = row >> lcd;
      if (t < 4) {
        const int g = g0 + t * 63 + offs + (row & (cnt - 1));
        const int ch0 = cidx[2 * g], ch1 = cidx[2 * g + 1];
        const int ty0 = ctype[2 * g], ty1 = ctype[2 * g + 1];
        const float c0v = cmask[2 * g], c1v = cmask[2 * g + 1];
        const unsigned short* pg = &pre[(size_t)g * 512 + hcol];
        const float iv = acc[mt][0][r] + bf2f(pg[0]) + bi;
        const float ov = acc[mt][1][r] + bf2f(pg[128]) + bo;
        const float uv = acc[mt][2][r] + bf2f(pg[256]) + bu;
        const float Xf = bf2f(pg[384]);
        const float f0 = acc[mt][3][r] + f0b;
        const float f1 = acc[mt][4][r] + f1b;
        const float fa = (ty0 == 0) ? f0 : f1;
        const float fb = (ty1 == 0) ? f0 : f1;
        const float ft0 = sigf(Xf + fa + bfv);
        const float ft1 = sigf(Xf + fb + bfv);
        const float ccell = ft0 * cbuf[(size_t)ch0 * 128 + hcol] * c0v +
                            ft1 * cbuf[(size_t)ch1 * 128 + hcol] * c1v;
        const float cn = sigf(iv) * tanhfast(uv) + ccell;
        const float hn = sigf(ov) * tanhfast(cn);
        cbuf[(size_t)g * 128 + hcol] = cn;
        hout[(size_t)g * 128 + hcol] = hn;
        hbuf[(size_t)g * 128 + hcol] = f2bf(hn);
      }
    }
  }
  __threadfence_block();
  __syncthreads();  // writes visible before next level's gather
}

__global__ __launch_bounds__(512, 1) void tree_kernel(
    const float* __restrict__ emb, const float* __restrict__ cmask,
    const int* __restrict__ cidx, const int* __restrict__ ctype,
    const unsigned short* __restrict__ BW, const unsigned short* __restrict__ BU,
    const float* __restrict__ b_iou, const float* __restrict__ ufb,
    const float* __restrict__ bf_,
    float* hout, float* cbuf, unsigned short* hbuf, unsigned short* pre) {
  __shared__ unsigned short Ar[128 * ASTR];     // 66 KB
  __shared__ unsigned short Bb[2][40 * 512];    // 80 KB

  const int tid = threadIdx.x;
  const int lane = tid & 63;
  const int w = tid >> 6;
  const int cl = lane & 15;
  const int rb = (lane >> 4) << 2;
  const int hcol = w * 16 + cl;
  const int g0 = blockIdx.x * 4 * 63;  // 4 trees per block

  // ================= Phase P: pre = emb@[Wiou|Wf] for internal nodes ======
#pragma unroll
  for (int c = 0; c < 4; ++c) {
    const int T = c * 8 + w;
    gld_lds16(&BW[(size_t)(T * 8) * 512 + lane * 8], &Bb[0][T * 512]);
  }
#pragma unroll
  for (int it = 0; it < 16; ++it) {  // stage 128 rows of emb (internal)
    const int f = it * 512 + tid;
    const int r = f >> 6, c4 = f & 63;
    const int t = r >> 5, idx = r & 31;
    const int g = g0 + t * 63 + 32 + (idx < 31 ? idx : 30);
    const float4 v = *(const float4*)&emb[(size_t)g * 256 + c4 * 4];
    ushort4 p;
    p.x = f2bf(v.x); p.y = f2bf(v.y); p.z = f2bf(v.z); p.w = f2bf(v.w);
    *(ushort4*)&Ar[r * ASTR + c4 * 4] = p;
  }
  __syncthreads();
  {
    f32x4 acc[8][4];
#pragma unroll
    for (int mt = 0; mt < 8; ++mt)
#pragma unroll
      for (int t = 0; t < 4; ++t) acc[mt][t] = (f32x4){0.f, 0.f, 0.f, 0.f};
    run_gemm<8, 4>(BW, Bb, Ar, lane, w, acc);
#pragma unroll
    for (int mt = 0; mt < 8; ++mt) {
#pragma unroll
      for (int r = 0; r < 4; ++r) {
        const int row = (mt << 4) + rb + r;
        const int t = row >> 5, idx = row & 31;
        if (idx < 31) {
          const int g = g0 + t * 63 + 32 + idx;
#pragma unroll
          for (int p = 0; p < 4; ++p)
            pre[(size_t)g * 512 + p * 128 + hcol] = f2bf(acc[mt][p][r]);
        }
      }
    }
  }
  __syncthreads();

  // ================= Phase L: leaves (iou only, no children) ==============
#pragma unroll
  for (int c = 0; c < 3; ++c) {
    const int T = c * 8 + w;
    gld_lds16(&BW[(size_t)(T * 8) * 512 + lane * 8], &Bb[0][T * 512]);
  }
#pragma unroll
  for (int it = 0; it < 16; ++it) {  // stage 128 leaf emb rows
    const int f = it * 512 + tid;
    const int r = f >> 6, c4 = f & 63;
    const int t = r >> 5, idx = r & 31;
    const int g = g0 + t * 63 + idx;
    const float4 v = *(const float4*)&emb[(size_t)g * 256 + c4 * 4];
    ushort4 p;
    p.x = f2bf(v.x); p.y = f2bf(v.y); p.z = f2bf(v.z); p.w = f2bf(v.w);
    *(ushort4*)&Ar[r * ASTR + c4 * 4] = p;
  }
  __syncthreads();
  {
    f32x4 acc[8][3];
#pragma unroll
    for (int mt = 0; mt < 8; ++mt)
#pragma unroll
      for (int t = 0; t < 3; ++t) acc[mt][t] = (f32x4){0.f, 0.f, 0.f, 0.f};
    run_gemm<8, 3>(BW, Bb, Ar, lane, w, acc);
    const float bi = b_iou[hcol], bo = b_iou[128 + hcol], bu = b_iou[256 + hcol];
#pragma unroll
    for (int mt = 0; mt < 8; ++mt) {
#pragma unroll
      for (int r = 0; r < 4; ++r) {
        const int row = (mt << 4) + rb + r;
        const int t = row >> 5, idx = row & 31;
        const int g = g0 + t * 63 + idx;
        const float cn = sigf(acc[mt][0][r] + bi) * tanhfast(acc[mt][2][r] + bu);
        const float hn = sigf(acc[mt][1][r] + bo) * tanhfast(cn);
        cbuf[(size_t)g * 128 + hcol] = cn;
        hout[(size_t)g * 128 + hcol] = hn;
        hbuf[(size_t)g * 128 + hcol] = f2bf(hn);
      }
    }
  }
  __threadfence_block();
  __syncthreads();  // leaf h/c visible before lvl1 gather

  // ================= Levels 1..5 ==========================================
  do_level<4>(4, 32, g0, cmask, cidx, ctype, BU, b_iou, ufb, bf_, pre,
              hout, cbuf, hbuf, Ar, Bb, tid, lane, w);
  do_level<2>(3, 48, g0, cmask, cidx, ctype, BU, b_iou, ufb, bf_, pre,
              hout, cbuf, hbuf, Ar, Bb, tid, lane, w);
  do_level<1>(2, 56, g0, cmask, cidx, ctype, BU, b_iou, ufb, bf_, pre,
              hout, cbuf, hbuf, Ar, Bb, tid, lane, w);
  do_level<1>(1, 60, g0, cmask, cidx, ctype, BU, b_iou, ufb, bf_, pre,
              hout, cbuf, hbuf, Ar, Bb, tid, lane, w);
  do_level<1>(0, 62, g0, cmask, cidx, ctype, BU, b_iou, ufb, bf_, pre,
              hout, cbuf, hbuf, Ar, Bb, tid, lane, w);
}

extern "C" void kernel_launch(void* const* d_in, const int* in_sizes, int n_in,
                              void* d_out, int out_size, void* d_ws, size_t ws_size,
                              hipStream_t stream) {
  (void)in_sizes; (void)n_in; (void)out_size; (void)ws_size;
  const float* emb   = (const float*)d_in[0];
  const float* cmask = (const float*)d_in[1];
  const float* W_iou = (const float*)d_in[2];
  const float* U_iou = (const float*)d_in[3];
  const float* b_iou = (const float*)d_in[4];
  const float* W_f   = (const float*)d_in[5];
  const float* U_f_w = (const float*)d_in[6];
  const float* U_f_b = (const float*)d_in[7];
  const float* b_f   = (const float*)d_in[8];
  const int* cidx    = (const int*)d_in[9];
  const int* ctype   = (const int*)d_in[10];
  float* hout = (float*)d_out;

  char* ws = (char*)d_ws;
  unsigned short* BW   = (unsigned short*)ws;                      // 262144 B
  unsigned short* BU   = (unsigned short*)(ws + 262144);           // 327680 B
  float* cbuf          = (float*)(ws + (1u << 20));                // 132 MB
  unsigned short* hbuf = (unsigned short*)(ws + 133169152ull);     // 66 MB
  unsigned short* pre  = (unsigned short*)(ws + 199229440ull);     // 264 MB

  prep_kernel<<<576, 512, 0, stream>>>(W_iou, U_iou, W_f, U_f_w, BW, BU);
  tree_kernel<<<1024, 512, 0, stream>>>(emb, cmask, cidx, ctype, BW, BU,
                                        b_iou, U_f_b, b_f, hout, cbuf, hbuf, pre);
}

// Round 8
// 456.783 us; speedup vs baseline: 1.2939x; 1.2939x over previous
//
#include <hip/hip_runtime.h>

// ---------------------------------------------------------------------------
// DepTreeLSTM on MI355X — round 8.
//   xp:  ALL nodes X = emb @ [W_iou|W_f] (K=256, N=512, node-order rows).
//        Leaf rows: fused LSTM epilogue (h,c). Internal rows: write pre bf16.
//   lvl d=1..5: A=[ht0|ht1] (K=256) x BU (640 cols) + pre-add epilogue.
// MT=8 (128 rows/block) for xp+lvl1+lvl2; tails MT=4/2/1 -> 256 blocks each.
// B streamed per-ks via global_load_lds double-buffer (R5 proven scheme).
// ws: BW 0 | BU 256K | cbuf f32 @1MB | hbuf bf16 @+132MB | pre bf16 @+198MB.
// ---------------------------------------------------------------------------

typedef float f32x4 __attribute__((ext_vector_type(4)));
typedef __bf16 bf16x8 __attribute__((ext_vector_type(8)));
typedef unsigned short u16x8 __attribute__((ext_vector_type(8)));

__device__ __forceinline__ unsigned short f2bf(float x) {
  unsigned int u = __float_as_uint(x);
  return (unsigned short)((u + 0x7fffu + ((u >> 16) & 1u)) >> 16);
}
__device__ __forceinline__ float bf2f(unsigned short u) {
  return __uint_as_float(((unsigned int)u) << 16);
}
__device__ __forceinline__ float sigf(float x) { return 1.f / (1.f + __expf(-x)); }
__device__ __forceinline__ float tanhfast(float x) {
  return 1.f - 2.f / (__expf(2.f * x) + 1.f);
}
__device__ __forceinline__ void gld_lds16(const unsigned short* g, unsigned short* l) {
  __builtin_amdgcn_global_load_lds((const __attribute__((address_space(1))) void*)g,
                                   (__attribute__((address_space(3))) void*)l, 16, 0, 0);
}

#define ASTR 264  // A row-image stride in shorts (K=256 + 8 pad)

// Fragment pack (K=256): X[((T*8+ks)*64+lane)*8+j], lane=kq*16+cl,
// col=T*16+cl, k=ks*32+kq*8+j.
// BW (32 tiles, N=512): col<384: W_iou[k][col]; else W_f[k][col-384].
// BU (40 tiles, N=640): col<384: U_iou[k][col]; else U_f_w[k][col-384].
__global__ void prep_kernel(const float* __restrict__ Wi, const float* __restrict__ Ui,
                            const float* __restrict__ Wf, const float* __restrict__ Uf,
                            unsigned short* __restrict__ BW, unsigned short* __restrict__ BU) {
  int idx = blockIdx.x * 512 + threadIdx.x;  // 0 .. 294911
  if (idx < 131072) {
    int j = idx & 7, lane = (idx >> 3) & 63, ks = (idx >> 9) & 7, T = idx >> 12;
    int cl = lane & 15, kq = lane >> 4;
    int c = T * 16 + cl, k = ks * 32 + kq * 8 + j;
    BW[idx] = f2bf((c < 384) ? Wi[k * 384 + c] : Wf[k * 128 + (c - 384)]);
  } else {
    int i2 = idx - 131072;
    int j = i2 & 7, lane = (i2 >> 3) & 63, ks = (i2 >> 9) & 7, T = i2 >> 12;
    int cl = lane & 15, kq = lane >> 4;
    int c = T * 16 + cl, k = ks * 32 + kq * 8 + j;
    BU[i2] = f2bf((c < 384) ? Ui[k * 384 + c] : Uf[k * 256 + (c - 384)]);
  }
}

// double-buffered per-ks B DMA + MFMA loop (8 ks-steps, K=256)
template <int MT, int NT>
__device__ __forceinline__ void run_gemm(const unsigned short* __restrict__ Bsrc,
                                         unsigned short* Bb,  // [2][NT*8*512]
                                         const unsigned short* Ar,
                                         int lane, int w, f32x4 (&acc)[MT][NT]) {
  constexpr int SL = NT * 8 * 512;
  const int cl = lane & 15, kq = lane >> 4;
  int cur = 0;
  for (int ks = 0; ks < 8; ++ks) {
    if (ks < 7) {
#pragma unroll
      for (int c = 0; c < NT; ++c) {
        const int T = c * 8 + w;
        gld_lds16(&Bsrc[(size_t)(T * 8 + ks + 1) * 512 + lane * 8],
                  &Bb[(size_t)(cur ^ 1) * SL + T * 512]);
      }
    }
    bf16x8 b[NT];
#pragma unroll
    for (int t = 0; t < NT; ++t)
      b[t] = *(const bf16x8*)&Bb[(size_t)cur * SL + (t * 8 + w) * 512 + lane * 8];
#pragma unroll
    for (int mt = 0; mt < MT; ++mt) {
      const bf16x8 a = *(const bf16x8*)&Ar[(mt * 16 + cl) * ASTR + ks * 32 + kq * 8];
#pragma unroll
      for (int t = 0; t < NT; ++t)
        acc[mt][t] = __builtin_amdgcn_mfma_f32_16x16x32_bf16(a, b[t], acc[mt][t], 0, 0, 0);
    }
    __syncthreads();
    cur ^= 1;
  }
}

// ---- xp: X = emb @ [Wiou|Wf] for ALL nodes; leaf epilogue or pre-write ----
__global__ __launch_bounds__(512, 2) void xp_kernel(
    const float* __restrict__ emb, const unsigned short* __restrict__ BW,
    const float* __restrict__ b_iou,
    float* __restrict__ hout, float* __restrict__ cbuf,
    unsigned short* __restrict__ hbuf, unsigned short* __restrict__ pre) {
  __shared__ unsigned short Ar[128 * ASTR];      // 66 KB
  __shared__ unsigned short Bb[2][4 * 8 * 512];  // 64 KB

  const int tid = threadIdx.x;
  const int lane = tid & 63;
  const int w = tid >> 6;
  const int m0 = blockIdx.x * 128;

  // DMA B slice ks=0 (overlaps A staging)
#pragma unroll
  for (int c = 0; c < 4; ++c) {
    const int T = c * 8 + w;
    gld_lds16(&BW[(size_t)(T * 8) * 512 + lane * 8], &Bb[0][T * 512]);
  }
  // stage 128 emb rows (node order: g = m0 + r), coalesced 1KB/row
#pragma unroll
  for (int it = 0; it < 16; ++it) {
    const int f = it * 512 + tid;
    const int r = f >> 6, c4 = f & 63;
    const float4 v = *(const float4*)&emb[(size_t)(m0 + r) * 256 + c4 * 4];
    ushort4 p;
    p.x = f2bf(v.x); p.y = f2bf(v.y); p.z = f2bf(v.z); p.w = f2bf(v.w);
    *(ushort4*)&Ar[r * ASTR + c4 * 4] = p;
  }
  __syncthreads();

  f32x4 acc[8][4];
#pragma unroll
  for (int mt = 0; mt < 8; ++mt)
#pragma unroll
    for (int t = 0; t < 4; ++t) acc[mt][t] = (f32x4){0.f, 0.f, 0.f, 0.f};
  run_gemm<8, 4>(BW, &Bb[0][0], Ar, lane, w, acc);

  const int cl = lane & 15;
  const int rb = (lane >> 4) << 2;
  const int hcol = w * 16 + cl;
  const float bi = b_iou[hcol], bo = b_iou[128 + hcol], bu = b_iou[256 + hcol];
#pragma unroll
  for (int mt = 0; mt < 8; ++mt) {
#pragma unroll
    for (int r = 0; r < 4; ++r) {
      const int g = m0 + (mt << 4) + rb + r;
      const int s = g % 63;  // node slot within tree
      if (s < 32) {          // leaf: full LSTM epilogue (no children)
        const float cn = sigf(acc[mt][0][r] + bi) * tanhfast(acc[mt][2][r] + bu);
        const float hn = sigf(acc[mt][1][r] + bo) * tanhfast(cn);
        cbuf[(size_t)g * 128 + hcol] = cn;
        hout[(size_t)g * 128 + hcol] = hn;
        hbuf[(size_t)g * 128 + hcol] = f2bf(hn);
      } else {               // internal: stash raw X (i,o,u,Xf)
#pragma unroll
        for (int p = 0; p < 4; ++p)
          pre[(size_t)g * 512 + p * 128 + hcol] = f2bf(acc[mt][p][r]);
      }
    }
  }
}

// ---- levels 1..5: A=[ht0|ht1] K=256, BU 40 tiles, NT=5, pre-add epilogue ----
template <int MT>
__global__ __launch_bounds__(512, 2) void lvl_kernel(
    const float* __restrict__ cmask,
    const int* __restrict__ cidx, const int* __restrict__ ctype,
    const unsigned short* __restrict__ BU,
    const float* __restrict__ b_iou, const float* __restrict__ ufb,
    const float* __restrict__ bf_,
    const unsigned short* __restrict__ pre,
    float* __restrict__ hout, float* __restrict__ cbuf,
    unsigned short* __restrict__ hbuf,
    int lc, int cntm1, int offs) {
  constexpr int ROWS = MT * 16;
  __shared__ unsigned short Ar[ROWS * ASTR];
  __shared__ unsigned short Bb[2][5 * 8 * 512];  // 80 KB

  const int tid = threadIdx.x;
  const int lane = tid & 63;
  const int w = tid >> 6;
  const int m0 = blockIdx.x * ROWS;

#pragma unroll
  for (int c = 0; c < 5; ++c) {
    const int T = c * 8 + w;
    gld_lds16(&BU[(size_t)(T * 8) * 512 + lane * 8], &Bb[0][T * 512]);
  }

  // stage A: group q (=wave) writes 32-col chunk q*32 (q<4: ht0, q>=4: ht1)
  {
    const int q = tid >> 6;
    const int sel = q >> 2;
    const int hc = (q & 3) * 32;
#pragma unroll
    for (int rep = 0; rep < (ROWS + 63) / 64; ++rep) {
      const int row = rep * 64 + (tid & 63);
      if (ROWS >= 64 || row < ROWS) {
        const int m = m0 + row;
        const int g = ((m >> lc) * 63) + offs + (m & cntm1);
        const int ch0 = cidx[2 * g], ch1 = cidx[2 * g + 1];
        const int ty0 = ctype[2 * g], ty1 = ctype[2 * g + 1];
        const float c0 = cmask[2 * g], c1 = cmask[2 * g + 1];
        const float wA = (ty0 == sel) ? c0 : 0.f;
        const float wB = (ty1 == sel) ? c1 : 0.f;
#pragma unroll
        for (int s = 0; s < 4; ++s) {
          const u16x8 va = *(const u16x8*)&hbuf[(size_t)ch0 * 128 + hc + 8 * s];
          const u16x8 vb = *(const u16x8*)&hbuf[(size_t)ch1 * 128 + hc + 8 * s];
          u16x8 o;
#pragma unroll
          for (int e = 0; e < 8; ++e) o[e] = f2bf(wA * bf2f(va[e]) + wB * bf2f(vb[e]));
          *(u16x8*)&Ar[row * ASTR + q * 32 + 8 * s] = o;
        }
      }
    }
  }
  __syncthreads();

  f32x4 acc[MT][5];
#pragma unroll
  for (int mt = 0; mt < MT; ++mt)
#pragma unroll
    for (int t = 0; t < 5; ++t) acc[mt][t] = (f32x4){0.f, 0.f, 0.f, 0.f};
  run_gemm<MT, 5>(BU, &Bb[0][0], Ar, lane, w, acc);

  const int cl = lane & 15;
  const int rb = (lane >> 4) << 2;
  const int hcol = w * 16 + cl;
  const float bi = b_iou[hcol], bo = b_iou[128 + hcol], bu = b_iou[256 + hcol];
  const float f0b = ufb[hcol], f1b = ufb[128 + hcol], bfv = bf_[hcol];
#pragma unroll
  for (int mt = 0; mt < MT; ++mt) {
#pragma unroll
    for (int r = 0; r < 4; ++r) {
      const int m = m0 + (mt << 4) + rb + r;
      const int g = ((m >> lc) * 63) + offs + (m & cntm1);
      const int ch0 = cidx[2 * g], ch1 = cidx[2 * g + 1];
      const int ty0 = ctype[2 * g], ty1 = ctype[2 * g + 1];
      const float c0v = cmask[2 * g], c1v = cmask[2 * g + 1];
      const unsigned short* pg = &pre[(size_t)g * 512 + hcol];
      const float iv = acc[mt][0][r] + bf2f(pg[0]) + bi;
      const float ov = acc[mt][1][r] + bf2f(pg[128]) + bo;
      const float uv = acc[mt][2][r] + bf2f(pg[256]) + bu;
      const float Xf = bf2f(pg[384]);
      const float f0 = acc[mt][3][r] + f0b;
      const float f1 = acc[mt][4][r] + f1b;
      const float fa = (ty0 == 0) ? f0 : f1;
      const float fb = (ty1 == 0) ? f0 : f1;
      const float ft0 = sigf(Xf + fa + bfv);
      const float ft1 = sigf(Xf + fb + bfv);
      const float ccell = ft0 * cbuf[(size_t)ch0 * 128 + hcol] * c0v +
                          ft1 * cbuf[(size_t)ch1 * 128 + hcol] * c1v;
      const float cn = sigf(iv) * tanhfast(uv) + ccell;
      const float hn = sigf(ov) * tanhfast(cn);
      cbuf[(size_t)g * 128 + hcol] = cn;
      hout[(size_t)g * 128 + hcol] = hn;
      hbuf[(size_t)g * 128 + hcol] = f2bf(hn);
    }
  }
}

extern "C" void kernel_launch(void* const* d_in, const int* in_sizes, int n_in,
                              void* d_out, int out_size, void* d_ws, size_t ws_size,
                              hipStream_t stream) {
  (void)in_sizes; (void)n_in; (void)out_size; (void)ws_size;
  const float* emb   = (const float*)d_in[0];
  const float* cmask = (const float*)d_in[1];
  const float* W_iou = (const float*)d_in[2];
  const float* U_iou = (const float*)d_in[3];
  const float* b_iou = (const float*)d_in[4];
  const float* W_f   = (const float*)d_in[5];
  const float* U_f_w = (const float*)d_in[6];
  const float* U_f_b = (const float*)d_in[7];
  const float* b_f   = (const float*)d_in[8];
  const int* cidx    = (const int*)d_in[9];
  const int* ctype   = (const int*)d_in[10];
  float* hout = (float*)d_out;

  char* ws = (char*)d_ws;
  unsigned short* BW   = (unsigned short*)ws;                      // 262144 B
  unsigned short* BU   = (unsigned short*)(ws + 262144);           // 327680 B
  float* cbuf          = (float*)(ws + (1u << 20));                // 132 MB
  unsigned short* hbuf = (unsigned short*)(ws + 133169152ull);     // 66 MB
  unsigned short* pre  = (unsigned short*)(ws + 199229440ull);     // 264 MB

  prep_kernel<<<576, 512, 0, stream>>>(W_iou, U_iou, W_f, U_f_w, BW, BU);

  xp_kernel<<<2016, 512, 0, stream>>>(emb, BW, b_iou, hout, cbuf, hbuf, pre);

  lvl_kernel<8><<<512, 512, 0, stream>>>(cmask, cidx, ctype, BU, b_iou, U_f_b, b_f,
                                         pre, hout, cbuf, hbuf, 4, 15, 32);
  lvl_kernel<8><<<256, 512, 0, stream>>>(cmask, cidx, ctype, BU, b_iou, U_f_b, b_f,
                                         pre, hout, cbuf, hbuf, 3, 7, 48);
  lvl_kernel<4><<<256, 512, 0, stream>>>(cmask, cidx, ctype, BU, b_iou, U_f_b, b_f,
                                         pre, hout, cbuf, hbuf, 2, 3, 56);
  lvl_kernel<2><<<256, 512, 0, stream>>>(cmask, cidx, ctype, BU, b_iou, U_f_b, b_f,
                                         pre, hout, cbuf, hbuf, 1, 1, 60);
  lvl_kernel<1><<<256, 512, 0, stream>>>(cmask, cidx, ctype, BU, b_iou, U_f_b, b_f,
                                         pre, hout, cbuf, hbuf, 0, 0, 62);
}

// Round 10
// 337.118 us; speedup vs baseline: 1.7532x; 1.3550x over previous
//
#include <hip/hip_runtime.h>

// ---------------------------------------------------------------------------
// DepTreeLSTM on MI355X — round 10: R9 with the WAR race fixed.
// Per level: A=[emb | ht0 | ht1] (K=512) x B (640 cols) via bf16 MFMA,
// fused in-register LSTM epilogue. Leaves: K=256, 384 cols.
// Block = 512 thr (8 waves) x 64 rows. Wave w owns col-tiles {t*8+w} ->
// single hcol = w*16+cl for parts i,o,u,f0,f1 -> in-register epilogue.
// K-loop: wave w DMAs exactly the B tiles it reads (no cross-wave sharing),
// NO __syncthreads in the loop: per-wave counted s_waitcnt vmcnt(NT).
// Refill of Bb[ks&1] is issued AFTER the MFMA phase (sched_barrier-fenced):
// MFMAs can't issue until the ds_reads returned, so the DMA's LDS write
// strictly follows read completion (WAR closed, unlike R9).
// ws: BTf bf16 fragment-packed at 0; c-state f32 [N][128] at 1MB.
// ---------------------------------------------------------------------------

typedef float f32x4 __attribute__((ext_vector_type(4)));
typedef __bf16 bf16x8 __attribute__((ext_vector_type(8)));

__device__ __forceinline__ unsigned short f2bf(float x) {
  unsigned int u = __float_as_uint(x);
  return (unsigned short)((u + 0x7fffu + ((u >> 16) & 1u)) >> 16);
}
__device__ __forceinline__ float sigf(float x) { return 1.f / (1.f + __expf(-x)); }
__device__ __forceinline__ float tanhfast(float x) {
  return 1.f - 2.f / (__expf(2.f * x) + 1.f);
}
__device__ __forceinline__ void gld_lds16(const unsigned short* g, unsigned short* l) {
  __builtin_amdgcn_global_load_lds((const __attribute__((address_space(1))) void*)g,
                                   (__attribute__((address_space(3))) void*)l, 16, 0, 0);
}

// Pack B in fragment order: BTf[((tile*16 + ks)*64 + lane)*8 + j]
// lane = kq*16 + cl, col = tile*16+cl, k = ks*32 + kq*8 + j  (K=512).
// col<384: W_iou/U_iou; col>=384: W_f (dup f0/f1) / U_f_w.
__global__ void prep_kernel(const float* __restrict__ Wi, const float* __restrict__ Ui,
                            const float* __restrict__ Wf, const float* __restrict__ Uf,
                            unsigned short* __restrict__ BTf) {
  int idx = blockIdx.x * 256 + threadIdx.x;  // 0 .. 40*16*64*8-1
  int j = idx & 7;
  int lane = (idx >> 3) & 63;
  int ks = (idx >> 9) & 15;
  int tile = idx >> 13;
  int cl = lane & 15, kq = lane >> 4;
  int col = tile * 16 + cl;
  int k = ks * 32 + kq * 8 + j;
  float v;
  if (k < 256) {
    v = (col < 384) ? Wi[k * 384 + col] : Wf[k * 128 + ((col - 384) & 127)];
  } else {
    int kk = k & 255;
    v = (col < 384) ? Ui[kk * 384 + col] : Uf[kk * 256 + (col - 384)];
  }
  BTf[idx] = f2bf(v);
}

// A-LDS fragment-order address (elements): ((mt*NKS + ks)*64 + kq*16 + r)*8 + j
template <int NKS>
__device__ __forceinline__ int a_addr(int rblk, int k) {
  int mt = rblk >> 4, r = rblk & 15;
  int ks = k >> 5, kq = (k >> 3) & 3, j = k & 7;
  return (((mt * NKS + ks) * 64 + (kq << 4) + r) << 3) + j;
}

template <bool LEAF>
__global__ __launch_bounds__(512, (LEAF ? 4 : 2)) void lvl_kernel(
    const float* __restrict__ emb, const float* __restrict__ cmask,
    const int* __restrict__ cidx, const int* __restrict__ ctype,
    const unsigned short* __restrict__ BTf,
    const float* __restrict__ b_iou, const float* __restrict__ ufb,
    const float* __restrict__ bf_,
    float* __restrict__ hout, float* __restrict__ cbuf,
    int lc, int cntm1, int offs) {
  constexpr int KD = LEAF ? 256 : 512;
  constexpr int NKS = KD / 32;          // 8 or 16
  constexpr int NT = LEAF ? 3 : 5;      // col-tiles per wave (24 / 40 total)
  constexpr int MT = 4;                 // 64 rows
  __shared__ unsigned short Alds[64 * KD];            // 32/64 KB
  __shared__ unsigned short Bb[2][NT * 8 * 512];      // 2x 24/40 KB

  const int tid = threadIdx.x;
  const int lane = tid & 63;
  const int w = tid >> 6;
  const int m0 = blockIdx.x * 64;

  // ---- prologue: issue B slices 0 and 1 (complete during A staging) ----
#pragma unroll
  for (int s = 0; s < 2; ++s)
#pragma unroll
    for (int c = 0; c < NT; ++c) {
      const int T = c * 8 + w;
      gld_lds16(&BTf[(size_t)(T * 16 + s) * 512 + lane * 8], &Bb[s][T * 512]);
    }

  // ---- stage emb (k<256) conflict-free fragment image ----
#pragma unroll
  for (int c = 0; c < MT; ++c) {
    const int ks_e = tid >> 6;          // 0..7
    const int lq = tid & 63;
    const int k0 = ks_e * 32 + (lq >> 4) * 8;
    const int rblk = c * 16 + (lq & 15);
    const int m = m0 + rblk;
    const int g = ((m >> lc) * 63) + offs + (m & cntm1);
    const float4 v0 = *(const float4*)&emb[(size_t)g * 256 + k0];
    const float4 v1 = *(const float4*)&emb[(size_t)g * 256 + k0 + 4];
    ushort4 p0, p1;
    p0.x = f2bf(v0.x); p0.y = f2bf(v0.y); p0.z = f2bf(v0.z); p0.w = f2bf(v0.w);
    p1.x = f2bf(v1.x); p1.y = f2bf(v1.y); p1.z = f2bf(v1.z); p1.w = f2bf(v1.w);
    unsigned short* dst = &Alds[((c * NKS + ks_e) * 64 + lq) * 8];
    *(ushort4*)dst = p0;
    *(ushort4*)(dst + 4) = p1;
  }

  // ---- stage ht0 (k 256..383), ht1 (k 384..511): weighted child-h gather ----
  if (!LEAF) {
    const int rblk = tid >> 3, q = tid & 7;   // 8 threads/row, 16 cols each
    const int m = m0 + rblk;
    const int g = ((m >> lc) * 63) + offs + (m & cntm1);
    const int ch0 = cidx[2 * g], ch1 = cidx[2 * g + 1];
    const int ty0 = ctype[2 * g], ty1 = ctype[2 * g + 1];
    const float c0 = cmask[2 * g], c1 = cmask[2 * g + 1];
    const float w00 = (ty0 == 0) ? c0 : 0.f, w01 = (ty1 == 0) ? c1 : 0.f;
    const float w10 = (ty0 == 1) ? c0 : 0.f, w11 = (ty1 == 1) ? c1 : 0.f;
#pragma unroll
    for (int jj = 0; jj < 4; ++jj) {
      const int j = q * 16 + jj * 4;
      float4 a = *(const float4*)&hout[(size_t)ch0 * 128 + j];
      float4 b = *(const float4*)&hout[(size_t)ch1 * 128 + j];
      ushort4 p0, p1;
      p0.x = f2bf(w00 * a.x + w01 * b.x);
      p0.y = f2bf(w00 * a.y + w01 * b.y);
      p0.z = f2bf(w00 * a.z + w01 * b.z);
      p0.w = f2bf(w00 * a.w + w01 * b.w);
      p1.x = f2bf(w10 * a.x + w11 * b.x);
      p1.y = f2bf(w10 * a.y + w11 * b.y);
      p1.z = f2bf(w10 * a.z + w11 * b.z);
      p1.w = f2bf(w10 * a.w + w11 * b.w);
      *(ushort4*)&Alds[a_addr<NKS>(rblk, 256 + j)] = p0;
      *(ushort4*)&Alds[a_addr<NKS>(rblk, 384 + j)] = p1;
    }
  }
  __syncthreads();   // A visible to all waves; drains prologue DMAs too

  // ---- barrier-free per-wave pipelined K-loop ----
  f32x4 acc[MT][NT];
#pragma unroll
  for (int mt = 0; mt < MT; ++mt)
#pragma unroll
    for (int t = 0; t < NT; ++t) acc[mt][t] = (f32x4){0.f, 0.f, 0.f, 0.f};

  const int cl = lane & 15;
#pragma unroll
  for (int ks = 0; ks < NKS; ++ks) {
    if (ks == NKS - 1) {
      __builtin_amdgcn_s_waitcnt(0x0F70);        // vmcnt(0): drain last slice
    } else {
      __builtin_amdgcn_s_waitcnt(0x0F70 | NT);   // slice ks landed; ks+1 in flight
    }
    __builtin_amdgcn_sched_barrier(0);
    bf16x8 b[NT];
#pragma unroll
    for (int t = 0; t < NT; ++t)
      b[t] = *(const bf16x8*)&Bb[ks & 1][(size_t)((t * 8 + w) * 64 + lane) * 8];
    __builtin_amdgcn_s_setprio(1);
#pragma unroll
    for (int mt = 0; mt < MT; ++mt) {
      const bf16x8 a = *(const bf16x8*)&Alds[((mt * NKS + ks) * 64 + lane) << 3];
#pragma unroll
      for (int t = 0; t < NT; ++t)
        acc[mt][t] = __builtin_amdgcn_mfma_f32_16x16x32_bf16(a, b[t], acc[mt][t], 0, 0, 0);
    }
    __builtin_amdgcn_s_setprio(0);
    __builtin_amdgcn_sched_barrier(0);
    // refill AFTER the MFMA phase: ds_reads of Bb[ks&1] have returned
    // (MFMAs consumed them), so the DMA write cannot beat them. (R9 bug fix)
    if (ks + 2 < NKS) {
#pragma unroll
      for (int c = 0; c < NT; ++c) {
        const int T = c * 8 + w;
        gld_lds16(&BTf[(size_t)(T * 16 + ks + 2) * 512 + lane * 8], &Bb[ks & 1][T * 512]);
      }
    }
  }

  // ---- in-register epilogue: wave w handles hcol = w*16 + cl ----
  // D layout: col = lane&15, row = 4*(lane>>4)+reg; parts i,o,u,f0,f1.
  const int rb = (lane >> 4) << 2;
  const int hcol = w * 16 + cl;
  const float bi = b_iou[hcol];
  const float bo = b_iou[128 + hcol];
  const float bu = b_iou[256 + hcol];
  float f0b = 0.f, f1b = 0.f, bfv = 0.f;
  if (!LEAF) { f0b = ufb[hcol]; f1b = ufb[128 + hcol]; bfv = bf_[hcol]; }

#pragma unroll
  for (int mt = 0; mt < MT; ++mt) {
#pragma unroll
    for (int r = 0; r < 4; ++r) {
      const int m = m0 + (mt << 4) + rb + r;
      const int g = ((m >> lc) * 63) + offs + (m & cntm1);
      const float iv = acc[mt][0][r] + bi;
      const float ov = acc[mt][1][r] + bo;
      const float uv = acc[mt][2][r] + bu;
      float cn;
      if (LEAF) {
        cn = sigf(iv) * tanhfast(uv);
      } else {
        const int ch0 = cidx[2 * g], ch1 = cidx[2 * g + 1];
        const int ty0 = ctype[2 * g], ty1 = ctype[2 * g + 1];
        const float c0v = cmask[2 * g], c1v = cmask[2 * g + 1];
        const float f0 = acc[mt][3][r] + f0b;
        const float f1 = acc[mt][4][r] + f1b;
        const float fa = (ty0 == 0) ? f0 : f1;
        const float fb = (ty1 == 0) ? f0 : f1;
        const float ft0 = sigf(fa + bfv);
        const float ft1 = sigf(fb + bfv);
        const float ccell = ft0 * cbuf[(size_t)ch0 * 128 + hcol] * c0v +
                            ft1 * cbuf[(size_t)ch1 * 128 + hcol] * c1v;
        cn = sigf(iv) * tanhfast(uv) + ccell;
      }
      const float hn = sigf(ov) * tanhfast(cn);
      cbuf[(size_t)g * 128 + hcol] = cn;
      hout[(size_t)g * 128 + hcol] = hn;
    }
  }
}

extern "C" void kernel_launch(void* const* d_in, const int* in_sizes, int n_in,
                              void* d_out, int out_size, void* d_ws, size_t ws_size,
                              hipStream_t stream) {
  (void)in_sizes; (void)n_in; (void)out_size; (void)ws_size;
  const float* emb   = (const float*)d_in[0];
  const float* cmask = (const float*)d_in[1];
  const float* W_iou = (const float*)d_in[2];
  const float* U_iou = (const float*)d_in[3];
  const float* b_iou = (const float*)d_in[4];
  const float* W_f   = (const float*)d_in[5];
  const float* U_f_w = (const float*)d_in[6];
  const float* U_f_b = (const float*)d_in[7];
  const float* b_f   = (const float*)d_in[8];
  const int* cidx    = (const int*)d_in[9];
  const int* ctype   = (const int*)d_in[10];
  float* hout = (float*)d_out;

  unsigned short* BTf = (unsigned short*)d_ws;                // 655360 B
  float* cbuf = (float*)((char*)d_ws + (size_t)(1 << 20));    // N*128*4 = 132 MB

  prep_kernel<<<1280, 256, 0, stream>>>(W_iou, U_iou, W_f, U_f_w, BTf);

  // level 0 (leaves): M=131072, 64-row blocks
  lvl_kernel<true><<<2048, 512, 0, stream>>>(emb, cmask, cidx, ctype, BTf, b_iou,
                                             U_f_b, b_f, hout, cbuf, 5, 31, 0);
  // levels 1..5
  lvl_kernel<false><<<1024, 512, 0, stream>>>(emb, cmask, cidx, ctype, BTf, b_iou,
                                              U_f_b, b_f, hout, cbuf, 4, 15, 32);
  lvl_kernel<false><<<512, 512, 0, stream>>>(emb, cmask, cidx, ctype, BTf, b_iou,
                                             U_f_b, b_f, hout, cbuf, 3, 7, 48);
  lvl_kernel<false><<<256, 512, 0, stream>>>(emb, cmask, cidx, ctype, BTf, b_iou,
                                             U_f_b, b_f, hout, cbuf, 2, 3, 56);
  lvl_kernel<false><<<128, 512, 0, stream>>>(emb, cmask, cidx, ctype, BTf, b_iou,
                                             U_f_b, b_f, hout, cbuf, 1, 1, 60);
  lvl_kernel<false><<<64, 512, 0, stream>>>(emb, cmask, cidx, ctype, BTf, b_iou,
                                            U_f_b, b_f, hout, cbuf, 0, 0, 62);
}

// Round 11
// 323.864 us; speedup vs baseline: 1.8249x; 1.0409x over previous
//
#include <hip/hip_runtime.h>

// ---------------------------------------------------------------------------
// DepTreeLSTM on MI355X — round 11: high-occupancy single-buffered variant.
// Per level: A=[emb | ht0 | ht1] (K=512) x B (640 cols) via bf16 MFMA,
// fused in-register LSTM epilogue. Leaves: K=256, 384 cols.
// Block = 512 thr (8 waves) x MT*16 rows. Wave w owns col-tiles {t*8+w} ->
// single hcol = w*16+cl for parts i,o,u,f0,f1 -> in-register epilogue.
// K-loop: single-buffered per-wave DMA (wave w streams exactly its tiles),
// no __syncthreads in loop. Per slice: vmcnt(0) -> b ds_reads -> lgkmcnt(0)
// -> issue next slice into same buffer (WAR-safe) -> MFMA. Exposed per-slice
// latency is hidden by CROSS-BLOCK TLP: non-leaf 72KB LDS -> 2 blocks/CU,
// leaf 40KB + bounds(512,6) -> 3 blocks/CU (vs R10's 1-2).
// ws: BTf bf16 fragment-packed at 0; c-state f32 [N][128] at 1MB.
// ---------------------------------------------------------------------------

typedef float f32x4 __attribute__((ext_vector_type(4)));
typedef __bf16 bf16x8 __attribute__((ext_vector_type(8)));

__device__ __forceinline__ unsigned short f2bf(float x) {
  unsigned int u = __float_as_uint(x);
  return (unsigned short)((u + 0x7fffu + ((u >> 16) & 1u)) >> 16);
}
__device__ __forceinline__ float sigf(float x) { return 1.f / (1.f + __expf(-x)); }
__device__ __forceinline__ float tanhfast(float x) {
  return 1.f - 2.f / (__expf(2.f * x) + 1.f);
}
__device__ __forceinline__ void gld_lds16(const unsigned short* g, unsigned short* l) {
  __builtin_amdgcn_global_load_lds((const __attribute__((address_space(1))) void*)g,
                                   (__attribute__((address_space(3))) void*)l, 16, 0, 0);
}

// Pack B in fragment order: BTf[((tile*16 + ks)*64 + lane)*8 + j]
// lane = kq*16 + cl, col = tile*16+cl, k = ks*32 + kq*8 + j  (K=512).
// col<384: W_iou/U_iou; col>=384: W_f (dup f0/f1) / U_f_w.
__global__ void prep_kernel(const float* __restrict__ Wi, const float* __restrict__ Ui,
                            const float* __restrict__ Wf, const float* __restrict__ Uf,
                            unsigned short* __restrict__ BTf) {
  int idx = blockIdx.x * 256 + threadIdx.x;  // 0 .. 40*16*64*8-1
  int j = idx & 7;
  int lane = (idx >> 3) & 63;
  int ks = (idx >> 9) & 15;
  int tile = idx >> 13;
  int cl = lane & 15, kq = lane >> 4;
  int col = tile * 16 + cl;
  int k = ks * 32 + kq * 8 + j;
  float v;
  if (k < 256) {
    v = (col < 384) ? Wi[k * 384 + col] : Wf[k * 128 + ((col - 384) & 127)];
  } else {
    int kk = k & 255;
    v = (col < 384) ? Ui[kk * 384 + col] : Uf[kk * 256 + (col - 384)];
  }
  BTf[idx] = f2bf(v);
}

// A-LDS fragment-order address (elements): ((mt*NKS + ks)*64 + kq*16 + r)*8 + j
template <int NKS>
__device__ __forceinline__ int a_addr(int rblk, int k) {
  int mt = rblk >> 4, r = rblk & 15;
  int ks = k >> 5, kq = (k >> 3) & 3, j = k & 7;
  return (((mt * NKS + ks) * 64 + (kq << 4) + r) << 3) + j;
}

template <bool LEAF, int MT, int WPE>
__global__ __launch_bounds__(512, WPE) void lvl_kernel(
    const float* __restrict__ emb, const float* __restrict__ cmask,
    const int* __restrict__ cidx, const int* __restrict__ ctype,
    const unsigned short* __restrict__ BTf,
    const float* __restrict__ b_iou, const float* __restrict__ ufb,
    const float* __restrict__ bf_,
    float* __restrict__ hout, float* __restrict__ cbuf,
    int lc, int cntm1, int offs) {
  constexpr int KD = LEAF ? 256 : 512;
  constexpr int NKS = KD / 32;          // 8 or 16
  constexpr int NT = LEAF ? 3 : 5;      // col-tiles per wave (24 / 40 total)
  constexpr int ROWS = MT * 16;
  __shared__ unsigned short Alds[ROWS * KD];       // 16-32 KB
  __shared__ unsigned short Bb[NT * 8 * 512];      // 24/40 KB single buffer

  const int tid = threadIdx.x;
  const int lane = tid & 63;
  const int w = tid >> 6;
  const int m0 = blockIdx.x * ROWS;

  // ---- prologue: issue B slice 0 (completes during A staging) ----
#pragma unroll
  for (int c = 0; c < NT; ++c) {
    const int T = c * 8 + w;
    gld_lds16(&BTf[(size_t)(T * 16) * 512 + lane * 8], &Bb[T * 512]);
  }

  // ---- stage emb (k<256) conflict-free fragment image ----
#pragma unroll
  for (int c = 0; c < MT; ++c) {
    const int ks_e = tid >> 6;          // 0..7
    const int lq = tid & 63;
    const int k0 = ks_e * 32 + (lq >> 4) * 8;
    const int rblk = c * 16 + (lq & 15);
    const int m = m0 + rblk;
    const int g = ((m >> lc) * 63) + offs + (m & cntm1);
    const float4 v0 = *(const float4*)&emb[(size_t)g * 256 + k0];
    const float4 v1 = *(const float4*)&emb[(size_t)g * 256 + k0 + 4];
    ushort4 p0, p1;
    p0.x = f2bf(v0.x); p0.y = f2bf(v0.y); p0.z = f2bf(v0.z); p0.w = f2bf(v0.w);
    p1.x = f2bf(v1.x); p1.y = f2bf(v1.y); p1.z = f2bf(v1.z); p1.w = f2bf(v1.w);
    unsigned short* dst = &Alds[((c * NKS + ks_e) * 64 + lq) * 8];
    *(ushort4*)dst = p0;
    *(ushort4*)(dst + 4) = p1;
  }

  // ---- stage ht0 (k 256..383), ht1 (k 384..511): weighted child-h gather ----
  if (!LEAF) {
    constexpr int TPR = 512 / ROWS;     // threads per row (16 or 32)
    constexpr int CPT = 128 / TPR;      // f32 cols per thread (8 or 4)
    const int rblk = tid / TPR, q = tid % TPR;
    const int m = m0 + rblk;
    const int g = ((m >> lc) * 63) + offs + (m & cntm1);
    const int ch0 = cidx[2 * g], ch1 = cidx[2 * g + 1];
    const int ty0 = ctype[2 * g], ty1 = ctype[2 * g + 1];
    const float c0 = cmask[2 * g], c1 = cmask[2 * g + 1];
    const float w00 = (ty0 == 0) ? c0 : 0.f, w01 = (ty1 == 0) ? c1 : 0.f;
    const float w10 = (ty0 == 1) ? c0 : 0.f, w11 = (ty1 == 1) ? c1 : 0.f;
#pragma unroll
    for (int jj = 0; jj < CPT / 4; ++jj) {
      const int j = q * CPT + jj * 4;
      float4 a = *(const float4*)&hout[(size_t)ch0 * 128 + j];
      float4 b = *(const float4*)&hout[(size_t)ch1 * 128 + j];
      ushort4 p0, p1;
      p0.x = f2bf(w00 * a.x + w01 * b.x);
      p0.y = f2bf(w00 * a.y + w01 * b.y);
      p0.z = f2bf(w00 * a.z + w01 * b.z);
      p0.w = f2bf(w00 * a.w + w01 * b.w);
      p1.x = f2bf(w10 * a.x + w11 * b.x);
      p1.y = f2bf(w10 * a.y + w11 * b.y);
      p1.z = f2bf(w10 * a.z + w11 * b.z);
      p1.w = f2bf(w10 * a.w + w11 * b.w);
      *(ushort4*)&Alds[a_addr<NKS>(rblk, 256 + j)] = p0;
      *(ushort4*)&Alds[a_addr<NKS>(rblk, 384 + j)] = p1;
    }
  }
  __syncthreads();   // A visible to all waves

  // ---- single-buffered per-wave pipelined K-loop (no block barriers) ----
  f32x4 acc[MT][NT];
#pragma unroll
  for (int mt = 0; mt < MT; ++mt)
#pragma unroll
    for (int t = 0; t < NT; ++t) acc[mt][t] = (f32x4){0.f, 0.f, 0.f, 0.f};

  const int cl = lane & 15;
#pragma unroll
  for (int ks = 0; ks < NKS; ++ks) {
    __builtin_amdgcn_s_waitcnt(0x0F70);    // vmcnt(0): slice ks landed in Bb
    __builtin_amdgcn_sched_barrier(0);
    bf16x8 b[NT];
#pragma unroll
    for (int t = 0; t < NT; ++t)
      b[t] = *(const bf16x8*)&Bb[(size_t)((t * 8 + w) * 64 + lane) * 8];
    __builtin_amdgcn_s_waitcnt(0xC07F);    // lgkmcnt(0): b fragments in regs
    __builtin_amdgcn_sched_barrier(0);
    // refill same buffer with slice ks+1 (b already in registers: WAR-safe)
    if (ks + 1 < NKS) {
#pragma unroll
      for (int c = 0; c < NT; ++c) {
        const int T = c * 8 + w;
        gld_lds16(&BTf[(size_t)(T * 16 + ks + 1) * 512 + lane * 8], &Bb[T * 512]);
      }
    }
    __builtin_amdgcn_s_setprio(1);
#pragma unroll
    for (int mt = 0; mt < MT; ++mt) {
      const bf16x8 a = *(const bf16x8*)&Alds[((mt * NKS + ks) * 64 + lane) << 3];
#pragma unroll
      for (int t = 0; t < NT; ++t)
        acc[mt][t] = __builtin_amdgcn_mfma_f32_16x16x32_bf16(a, b[t], acc[mt][t], 0, 0, 0);
    }
    __builtin_amdgcn_s_setprio(0);
  }

  // ---- in-register epilogue: wave w handles hcol = w*16 + cl ----
  // D layout: col = lane&15, row = 4*(lane>>4)+reg; parts i,o,u,f0,f1.
  const int rb = (lane >> 4) << 2;
  const int hcol = w * 16 + cl;
  const float bi = b_iou[hcol];
  const float bo = b_iou[128 + hcol];
  const float bu = b_iou[256 + hcol];
  float f0b = 0.f, f1b = 0.f, bfv = 0.f;
  if (!LEAF) { f0b = ufb[hcol]; f1b = ufb[128 + hcol]; bfv = bf_[hcol]; }

#pragma unroll
  for (int mt = 0; mt < MT; ++mt) {
#pragma unroll
    for (int r = 0; r < 4; ++r) {
      const int m = m0 + (mt << 4) + rb + r;
      const int g = ((m >> lc) * 63) + offs + (m & cntm1);
      const float iv = acc[mt][0][r] + bi;
      const float ov = acc[mt][1][r] + bo;
      const float uv = acc[mt][2][r] + bu;
      float cn;
      if (LEAF) {
        cn = sigf(iv) * tanhfast(uv);
      } else {
        const int ch0 = cidx[2 * g], ch1 = cidx[2 * g + 1];
        const int ty0 = ctype[2 * g], ty1 = ctype[2 * g + 1];
        const float c0v = cmask[2 * g], c1v = cmask[2 * g + 1];
        const float f0 = acc[mt][3][r] + f0b;
        const float f1 = acc[mt][4][r] + f1b;
        const float fa = (ty0 == 0) ? f0 : f1;
        const float fb = (ty1 == 0) ? f0 : f1;
        const float ft0 = sigf(fa + bfv);
        const float ft1 = sigf(fb + bfv);
        const float ccell = ft0 * cbuf[(size_t)ch0 * 128 + hcol] * c0v +
                            ft1 * cbuf[(size_t)ch1 * 128 + hcol] * c1v;
        cn = sigf(iv) * tanhfast(uv) + ccell;
      }
      const float hn = sigf(ov) * tanhfast(cn);
      cbuf[(size_t)g * 128 + hcol] = cn;
      hout[(size_t)g * 128 + hcol] = hn;
    }
  }
}

extern "C" void kernel_launch(void* const* d_in, const int* in_sizes, int n_in,
                              void* d_out, int out_size, void* d_ws, size_t ws_size,
                              hipStream_t stream) {
  (void)in_sizes; (void)n_in; (void)out_size; (void)ws_size;
  const float* emb   = (const float*)d_in[0];
  const float* cmask = (const float*)d_in[1];
  const float* W_iou = (const float*)d_in[2];
  const float* U_iou = (const float*)d_in[3];
  const float* b_iou = (const float*)d_in[4];
  const float* W_f   = (const float*)d_in[5];
  const float* U_f_w = (const float*)d_in[6];
  const float* U_f_b = (const float*)d_in[7];
  const float* b_f   = (const float*)d_in[8];
  const int* cidx    = (const int*)d_in[9];
  const int* ctype   = (const int*)d_in[10];
  float* hout = (float*)d_out;

  unsigned short* BTf = (unsigned short*)d_ws;                // 655360 B
  float* cbuf = (float*)((char*)d_ws + (size_t)(1 << 20));    // N*128*4 = 132 MB

  prep_kernel<<<1280, 256, 0, stream>>>(W_iou, U_iou, W_f, U_f_w, BTf);

  // level 0 (leaves): M=131072, 32-row blocks, 3 blocks/CU
  lvl_kernel<true, 2, 6><<<4096, 512, 0, stream>>>(emb, cmask, cidx, ctype, BTf, b_iou,
                                                   U_f_b, b_f, hout, cbuf, 5, 31, 0);
  // levels 1..5
  lvl_kernel<false, 2, 4><<<2048, 512, 0, stream>>>(emb, cmask, cidx, ctype, BTf, b_iou,
                                                    U_f_b, b_f, hout, cbuf, 4, 15, 32);
  lvl_kernel<false, 2, 4><<<1024, 512, 0, stream>>>(emb, cmask, cidx, ctype, BTf, b_iou,
                                                    U_f_b, b_f, hout, cbuf, 3, 7, 48);
  lvl_kernel<false, 2, 4><<<512, 512, 0, stream>>>(emb, cmask, cidx, ctype, BTf, b_iou,
                                                   U_f_b, b_f, hout, cbuf, 2, 3, 56);
  lvl_kernel<false, 1, 4><<<512, 512, 0, stream>>>(emb, cmask, cidx, ctype, BTf, b_iou,
                                                   U_f_b, b_f, hout, cbuf, 1, 1, 60);
  lvl_kernel<false, 1, 4><<<256, 512, 0, stream>>>(emb, cmask, cidx, ctype, BTf, b_iou,
                                                   U_f_b, b_f, hout, cbuf, 0, 0, 62);
}

// Round 12
// 317.823 us; speedup vs baseline: 1.8596x; 1.0190x over previous
//
#include <hip/hip_runtime.h>

// ---------------------------------------------------------------------------
// DepTreeLSTM on MI355X — round 12: B streamed straight into REGISTERS.
// Per level: A=[emb | ht0 | ht1] (K=512) x B (640 cols) via bf16 MFMA,
// fused in-register LSTM epilogue. Leaves: K=256, 384 cols.
// Block = 512 thr (8 waves) x MT*16 rows. Wave w owns col-tiles {t*8+w} ->
// single hcol = w*16+cl for parts i,o,u,f0,f1 -> in-register epilogue.
// Since R5 each wave reads ONLY its own B tiles -> the LDS round-trip for B
// was pure overhead. Now: per-lane global_load_dwordx4 (base + lane*16,
// coalesced 1KB/wave) into a compiler-scheduled bA/bB register ping-pong
// (fully unrolled => static indexing). No manual waitcnt, no LDS for B,
// no WAR hazard (register renaming). LDS = A only (16-32 KB).
// Occupancy: non-leaf bounds(512,4) ~4 waves/SIMD; leaf bounds(512,6).
// ws: BTf bf16 fragment-packed at 0; c-state f32 [N][128] at 1MB.
// ---------------------------------------------------------------------------

typedef float f32x4 __attribute__((ext_vector_type(4)));
typedef __bf16 bf16x8 __attribute__((ext_vector_type(8)));

__device__ __forceinline__ unsigned short f2bf(float x) {
  unsigned int u = __float_as_uint(x);
  return (unsigned short)((u + 0x7fffu + ((u >> 16) & 1u)) >> 16);
}
__device__ __forceinline__ float sigf(float x) { return 1.f / (1.f + __expf(-x)); }
__device__ __forceinline__ float tanhfast(float x) {
  return 1.f - 2.f / (__expf(2.f * x) + 1.f);
}

// Pack B in fragment order: BTf[((tile*16 + ks)*64 + lane)*8 + j]
// lane = kq*16 + cl, col = tile*16+cl, k = ks*32 + kq*8 + j  (K=512).
// col<384: W_iou/U_iou; col>=384: W_f (dup f0/f1) / U_f_w.
__global__ void prep_kernel(const float* __restrict__ Wi, const float* __restrict__ Ui,
                            const float* __restrict__ Wf, const float* __restrict__ Uf,
                            unsigned short* __restrict__ BTf) {
  int idx = blockIdx.x * 256 + threadIdx.x;  // 0 .. 40*16*64*8-1
  int j = idx & 7;
  int lane = (idx >> 3) & 63;
  int ks = (idx >> 9) & 15;
  int tile = idx >> 13;
  int cl = lane & 15, kq = lane >> 4;
  int col = tile * 16 + cl;
  int k = ks * 32 + kq * 8 + j;
  float v;
  if (k < 256) {
    v = (col < 384) ? Wi[k * 384 + col] : Wf[k * 128 + ((col - 384) & 127)];
  } else {
    int kk = k & 255;
    v = (col < 384) ? Ui[kk * 384 + col] : Uf[kk * 256 + (col - 384)];
  }
  BTf[idx] = f2bf(v);
}

// A-LDS fragment-order address (elements): ((mt*NKS + ks)*64 + kq*16 + r)*8 + j
template <int NKS>
__device__ __forceinline__ int a_addr(int rblk, int k) {
  int mt = rblk >> 4, r = rblk & 15;
  int ks = k >> 5, kq = (k >> 3) & 3, j = k & 7;
  return (((mt * NKS + ks) * 64 + (kq << 4) + r) << 3) + j;
}

template <bool LEAF, int MT, int WPE>
__global__ __launch_bounds__(512, WPE) void lvl_kernel(
    const float* __restrict__ emb, const float* __restrict__ cmask,
    const int* __restrict__ cidx, const int* __restrict__ ctype,
    const unsigned short* __restrict__ BTf,
    const float* __restrict__ b_iou, const float* __restrict__ ufb,
    const float* __restrict__ bf_,
    float* __restrict__ hout, float* __restrict__ cbuf,
    int lc, int cntm1, int offs) {
  constexpr int KD = LEAF ? 256 : 512;
  constexpr int NKS = KD / 32;          // 8 or 16
  constexpr int NT = LEAF ? 3 : 5;      // col-tiles per wave (24 / 40 total)
  constexpr int ROWS = MT * 16;
  __shared__ unsigned short Alds[ROWS * KD];   // 16-32 KB (A only)

  const int tid = threadIdx.x;
  const int lane = tid & 63;
  const int w = tid >> 6;
  const int m0 = blockIdx.x * ROWS;

  // ---- stage emb (k<256) conflict-free fragment image ----
#pragma unroll
  for (int c = 0; c < MT; ++c) {
    const int ks_e = tid >> 6;          // 0..7
    const int lq = tid & 63;
    const int k0 = ks_e * 32 + (lq >> 4) * 8;
    const int rblk = c * 16 + (lq & 15);
    const int m = m0 + rblk;
    const int g = ((m >> lc) * 63) + offs + (m & cntm1);
    const float4 v0 = *(const float4*)&emb[(size_t)g * 256 + k0];
    const float4 v1 = *(const float4*)&emb[(size_t)g * 256 + k0 + 4];
    ushort4 p0, p1;
    p0.x = f2bf(v0.x); p0.y = f2bf(v0.y); p0.z = f2bf(v0.z); p0.w = f2bf(v0.w);
    p1.x = f2bf(v1.x); p1.y = f2bf(v1.y); p1.z = f2bf(v1.z); p1.w = f2bf(v1.w);
    unsigned short* dst = &Alds[((c * NKS + ks_e) * 64 + lq) * 8];
    *(ushort4*)dst = p0;
    *(ushort4*)(dst + 4) = p1;
  }

  // ---- stage ht0 (k 256..383), ht1 (k 384..511): weighted child-h gather ----
  if (!LEAF) {
    constexpr int TPR = 512 / ROWS;     // threads per row (16 or 32)
    constexpr int CPT = 128 / TPR;      // f32 cols per thread (8 or 4)
    const int rblk = tid / TPR, q = tid % TPR;
    const int m = m0 + rblk;
    const int g = ((m >> lc) * 63) + offs + (m & cntm1);
    const int ch0 = cidx[2 * g], ch1 = cidx[2 * g + 1];
    const int ty0 = ctype[2 * g], ty1 = ctype[2 * g + 1];
    const float c0 = cmask[2 * g], c1 = cmask[2 * g + 1];
    const float w00 = (ty0 == 0) ? c0 : 0.f, w01 = (ty1 == 0) ? c1 : 0.f;
    const float w10 = (ty0 == 1) ? c0 : 0.f, w11 = (ty1 == 1) ? c1 : 0.f;
#pragma unroll
    for (int jj = 0; jj < CPT / 4; ++jj) {
      const int j = q * CPT + jj * 4;
      float4 a = *(const float4*)&hout[(size_t)ch0 * 128 + j];
      float4 b = *(const float4*)&hout[(size_t)ch1 * 128 + j];
      ushort4 p0, p1;
      p0.x = f2bf(w00 * a.x + w01 * b.x);
      p0.y = f2bf(w00 * a.y + w01 * b.y);
      p0.z = f2bf(w00 * a.z + w01 * b.z);
      p0.w = f2bf(w00 * a.w + w01 * b.w);
      p1.x = f2bf(w10 * a.x + w11 * b.x);
      p1.y = f2bf(w10 * a.y + w11 * b.y);
      p1.z = f2bf(w10 * a.z + w11 * b.z);
      p1.w = f2bf(w10 * a.w + w11 * b.w);
      *(ushort4*)&Alds[a_addr<NKS>(rblk, 256 + j)] = p0;
      *(ushort4*)&Alds[a_addr<NKS>(rblk, 384 + j)] = p1;
    }
  }
  __syncthreads();   // A visible to all waves

  // ---- K-loop: B in registers, compiler-scheduled ping-pong ----
  f32x4 acc[MT][NT];
#pragma unroll
  for (int mt = 0; mt < MT; ++mt)
#pragma unroll
    for (int t = 0; t < NT; ++t) acc[mt][t] = (f32x4){0.f, 0.f, 0.f, 0.f};

  // per-lane B base: tile stride 8192 elems (16 slices * 512), wave picks
  // tiles {t*8+w}; within a tile, slice ks at ks*512 + lane*8.
  const unsigned short* Bw = BTf + (size_t)w * 8192 + lane * 8;

  bf16x8 bA[NT], bB[NT];
#pragma unroll
  for (int t = 0; t < NT; ++t)
    bA[t] = *(const bf16x8*)&Bw[(size_t)t * 65536];

  auto step = [&](bf16x8(&cur)[NT], bf16x8(&nxt)[NT], int ks) {
    if (ks + 1 < NKS) {
#pragma unroll
      for (int t = 0; t < NT; ++t)
        nxt[t] = *(const bf16x8*)&Bw[(size_t)t * 65536 + (ks + 1) * 512];
    }
    __builtin_amdgcn_s_setprio(1);
#pragma unroll
    for (int mt = 0; mt < MT; ++mt) {
      const bf16x8 a = *(const bf16x8*)&Alds[((mt * NKS + ks) * 64 + lane) << 3];
#pragma unroll
      for (int t = 0; t < NT; ++t)
        acc[mt][t] = __builtin_amdgcn_mfma_f32_16x16x32_bf16(a, cur[t], acc[mt][t], 0, 0, 0);
    }
    __builtin_amdgcn_s_setprio(0);
  };
#pragma unroll
  for (int ks2 = 0; ks2 < NKS / 2; ++ks2) {
    step(bA, bB, 2 * ks2);
    step(bB, bA, 2 * ks2 + 1);
  }

  // ---- in-register epilogue: wave w handles hcol = w*16 + cl ----
  // D layout: col = lane&15, row = 4*(lane>>4)+reg; parts i,o,u,f0,f1.
  const int cl = lane & 15;
  const int rb = (lane >> 4) << 2;
  const int hcol = w * 16 + cl;
  const float bi = b_iou[hcol];
  const float bo = b_iou[128 + hcol];
  const float bu = b_iou[256 + hcol];
  float f0b = 0.f, f1b = 0.f, bfv = 0.f;
  if (!LEAF) { f0b = ufb[hcol]; f1b = ufb[128 + hcol]; bfv = bf_[hcol]; }

#pragma unroll
  for (int mt = 0; mt < MT; ++mt) {
#pragma unroll
    for (int r = 0; r < 4; ++r) {
      const int m = m0 + (mt << 4) + rb + r;
      const int g = ((m >> lc) * 63) + offs + (m & cntm1);
      const float iv = acc[mt][0][r] + bi;
      const float ov = acc[mt][1][r] + bo;
      const float uv = acc[mt][2][r] + bu;
      float cn;
      if (LEAF) {
        cn = sigf(iv) * tanhfast(uv);
      } else {
        const int ch0 = cidx[2 * g], ch1 = cidx[2 * g + 1];
        const int ty0 = ctype[2 * g], ty1 = ctype[2 * g + 1];
        const float c0v = cmask[2 * g], c1v = cmask[2 * g + 1];
        const float f0 = acc[mt][3][r] + f0b;
        const float f1 = acc[mt][4][r] + f1b;
        const float fa = (ty0 == 0) ? f0 : f1;
        const float fb = (ty1 == 0) ? f0 : f1;
        const float ft0 = sigf(fa + bfv);
        const float ft1 = sigf(fb + bfv);
        const float ccell = ft0 * cbuf[(size_t)ch0 * 128 + hcol] * c0v +
                            ft1 * cbuf[(size_t)ch1 * 128 + hcol] * c1v;
        cn = sigf(iv) * tanhfast(uv) + ccell;
      }
      const float hn = sigf(ov) * tanhfast(cn);
      cbuf[(size_t)g * 128 + hcol] = cn;
      hout[(size_t)g * 128 + hcol] = hn;
    }
  }
}

extern "C" void kernel_launch(void* const* d_in, const int* in_sizes, int n_in,
                              void* d_out, int out_size, void* d_ws, size_t ws_size,
                              hipStream_t stream) {
  (void)in_sizes; (void)n_in; (void)out_size; (void)ws_size;
  const float* emb   = (const float*)d_in[0];
  const float* cmask = (const float*)d_in[1];
  const float* W_iou = (const float*)d_in[2];
  const float* U_iou = (const float*)d_in[3];
  const float* b_iou = (const float*)d_in[4];
  const float* W_f   = (const float*)d_in[5];
  const float* U_f_w = (const float*)d_in[6];
  const float* U_f_b = (const float*)d_in[7];
  const float* b_f   = (const float*)d_in[8];
  const int* cidx    = (const int*)d_in[9];
  const int* ctype   = (const int*)d_in[10];
  float* hout = (float*)d_out;

  unsigned short* BTf = (unsigned short*)d_ws;                // 655360 B
  float* cbuf = (float*)((char*)d_ws + (size_t)(1 << 20));    // N*128*4 = 132 MB

  prep_kernel<<<1280, 256, 0, stream>>>(W_iou, U_iou, W_f, U_f_w, BTf);

  // level 0 (leaves): M=131072, 32-row blocks
  lvl_kernel<true, 2, 6><<<4096, 512, 0, stream>>>(emb, cmask, cidx, ctype, BTf, b_iou,
                                                   U_f_b, b_f, hout, cbuf, 5, 31, 0);
  // levels 1..5
  lvl_kernel<false, 2, 4><<<2048, 512, 0, stream>>>(emb, cmask, cidx, ctype, BTf, b_iou,
                                                    U_f_b, b_f, hout, cbuf, 4, 15, 32);
  lvl_kernel<false, 2, 4><<<1024, 512, 0, stream>>>(emb, cmask, cidx, ctype, BTf, b_iou,
                                                    U_f_b, b_f, hout, cbuf, 3, 7, 48);
  lvl_kernel<false, 2, 4><<<512, 512, 0, stream>>>(emb, cmask, cidx, ctype, BTf, b_iou,
                                                   U_f_b, b_f, hout, cbuf, 2, 3, 56);
  lvl_kernel<false, 1, 4><<<512, 512, 0, stream>>>(emb, cmask, cidx, ctype, BTf, b_iou,
                                                   U_f_b, b_f, hout, cbuf, 1, 1, 60);
  lvl_kernel<false, 1, 4><<<256, 512, 0, stream>>>(emb, cmask, cidx, ctype, BTf, b_iou,
                                                   U_f_b, b_f, hout, cbuf, 0, 0, 62);
}

// Round 13
// 265.797 us; speedup vs baseline: 2.2236x; 1.1957x over previous
//
#include <hip/hip_runtime.h>

// ---------------------------------------------------------------------------
// DepTreeLSTM on MI355X — round 13: tree-local leaf+lvl1 fusion.
// fused_kernel: block = 2 trees (64 leaves + 32 lvl1 nodes), 2048 blocks.
//   Phase 0: leaf GEMM (MT=4, K=256, NT=3) + LSTM epilogue.
//            h -> hout(HBM) + LDS hstash(bf16); c -> LDS cstash(f32) ONLY.
//   Phase 1: lvl1 GEMM (MT=2, K=512, NT=5). ht from hstash, c_cell from
//            cstash (children are in-block by topology). h,c -> HBM.
// Tails lvl2..5: R12's lvl_kernel verbatim. B streamed to registers (R12).
// LDS: A 32K + hstash 16K + cstash 32K = 80 KB -> 2 blocks/CU.
// ws: BTf bf16 fragment-packed at 0; c-state f32 [N][128] at 1MB.
// ---------------------------------------------------------------------------

typedef float f32x4 __attribute__((ext_vector_type(4)));
typedef __bf16 bf16x8 __attribute__((ext_vector_type(8)));
typedef unsigned short u16x8 __attribute__((ext_vector_type(8)));

__device__ __forceinline__ unsigned short f2bf(float x) {
  unsigned int u = __float_as_uint(x);
  return (unsigned short)((u + 0x7fffu + ((u >> 16) & 1u)) >> 16);
}
__device__ __forceinline__ float bf2f(unsigned short u) {
  return __uint_as_float(((unsigned int)u) << 16);
}
__device__ __forceinline__ float sigf(float x) { return 1.f / (1.f + __expf(-x)); }
__device__ __forceinline__ float tanhfast(float x) {
  return 1.f - 2.f / (__expf(2.f * x) + 1.f);
}

// Pack B in fragment order: BTf[((tile*16 + ks)*64 + lane)*8 + j]
// lane = kq*16 + cl, col = tile*16+cl, k = ks*32 + kq*8 + j  (K=512).
// col<384: W_iou/U_iou; col>=384: W_f (dup f0/f1) / U_f_w.
__global__ void prep_kernel(const float* __restrict__ Wi, const float* __restrict__ Ui,
                            const float* __restrict__ Wf, const float* __restrict__ Uf,
                            unsigned short* __restrict__ BTf) {
  int idx = blockIdx.x * 256 + threadIdx.x;
  int j = idx & 7;
  int lane = (idx >> 3) & 63;
  int ks = (idx >> 9) & 15;
  int tile = idx >> 13;
  int cl = lane & 15, kq = lane >> 4;
  int col = tile * 16 + cl;
  int k = ks * 32 + kq * 8 + j;
  float v;
  if (k < 256) {
    v = (col < 384) ? Wi[k * 384 + col] : Wf[k * 128 + ((col - 384) & 127)];
  } else {
    int kk = k & 255;
    v = (col < 384) ? Ui[kk * 384 + col] : Uf[kk * 256 + (col - 384)];
  }
  BTf[idx] = f2bf(v);
}

// A-LDS fragment-order address (elements): ((mt*NKS + ks)*64 + kq*16 + r)*8 + j
template <int NKS>
__device__ __forceinline__ int a_addr(int rblk, int k) {
  int mt = rblk >> 4, r = rblk & 15;
  int ks = k >> 5, kq = (k >> 3) & 3, j = k & 7;
  return (((mt * NKS + ks) * 64 + (kq << 4) + r) << 3) + j;
}

// ======================= fused leaf + lvl1 kernel ==========================
__global__ __launch_bounds__(512, 4) void fused_kernel(
    const float* __restrict__ emb, const float* __restrict__ cmask,
    const int* __restrict__ ctype,
    const unsigned short* __restrict__ BTf,
    const float* __restrict__ b_iou, const float* __restrict__ ufb,
    const float* __restrict__ bf_,
    float* __restrict__ hout, float* __restrict__ cbuf) {
  __shared__ unsigned short Alds[16384];   // 32 KB: leaf 64xK256 / lvl1 32xK512
  __shared__ unsigned short hstash[8192];  // 16 KB: 64 leaves x 128 bf16
  __shared__ float cstash[8192];           // 32 KB: 64 leaves x 128 f32

  const int tid = threadIdx.x;
  const int lane = tid & 63;
  const int w = tid >> 6;
  const int cl = lane & 15;
  const int rb = (lane >> 4) << 2;
  const int hcol = w * 16 + cl;
  const int g0 = blockIdx.x * 126;       // two trees: 2b, 2b+1

  const unsigned short* Bw = BTf + (size_t)w * 8192 + lane * 8;

  // ---- Phase 0 staging: 64 leaf emb rows, fragment image (NKS=8) ----
#pragma unroll
  for (int c = 0; c < 4; ++c) {
    const int ks_e = tid >> 6;
    const int lq = tid & 63;
    const int k0 = ks_e * 32 + (lq >> 4) * 8;
    const int rblk = c * 16 + (lq & 15);
    const int g = g0 + (rblk >> 5) * 63 + (rblk & 31);
    const float4 v0 = *(const float4*)&emb[(size_t)g * 256 + k0];
    const float4 v1 = *(const float4*)&emb[(size_t)g * 256 + k0 + 4];
    ushort4 p0, p1;
    p0.x = f2bf(v0.x); p0.y = f2bf(v0.y); p0.z = f2bf(v0.z); p0.w = f2bf(v0.w);
    p1.x = f2bf(v1.x); p1.y = f2bf(v1.y); p1.z = f2bf(v1.z); p1.w = f2bf(v1.w);
    unsigned short* dst = &Alds[((c * 8 + ks_e) * 64 + lq) * 8];
    *(ushort4*)dst = p0;
    *(ushort4*)(dst + 4) = p1;
  }
  __syncthreads();

  // ---- Phase 0 GEMM: MT=4, NT=3, slices 0..7 ----
  {
    f32x4 acc[4][3];
#pragma unroll
    for (int mt = 0; mt < 4; ++mt)
#pragma unroll
      for (int t = 0; t < 3; ++t) acc[mt][t] = (f32x4){0.f, 0.f, 0.f, 0.f};
    bf16x8 bA[3], bB[3];
#pragma unroll
    for (int t = 0; t < 3; ++t) bA[t] = *(const bf16x8*)&Bw[(size_t)t * 65536];
#pragma unroll
    for (int ks2 = 0; ks2 < 4; ++ks2) {
#pragma unroll
      for (int half = 0; half < 2; ++half) {
        const int ks = 2 * ks2 + half;
        bf16x8* cur = half ? bB : bA;
        bf16x8* nxt = half ? bA : bB;
        if (ks + 1 < 8) {
#pragma unroll
          for (int t = 0; t < 3; ++t)
            nxt[t] = *(const bf16x8*)&Bw[(size_t)t * 65536 + (ks + 1) * 512];
        }
        __builtin_amdgcn_s_setprio(1);
#pragma unroll
        for (int mt = 0; mt < 4; ++mt) {
          const bf16x8 a = *(const bf16x8*)&Alds[((mt * 8 + ks) * 64 + lane) << 3];
#pragma unroll
          for (int t = 0; t < 3; ++t)
            acc[mt][t] = __builtin_amdgcn_mfma_f32_16x16x32_bf16(a, cur[t], acc[mt][t], 0, 0, 0);
        }
        __builtin_amdgcn_s_setprio(0);
      }
    }
    // ---- Phase 0 epilogue: h->hout+hstash, c->cstash only ----
    const float bi = b_iou[hcol], bo = b_iou[128 + hcol], bu = b_iou[256 + hcol];
#pragma unroll
    for (int mt = 0; mt < 4; ++mt) {
#pragma unroll
      for (int r = 0; r < 4; ++r) {
        const int row = (mt << 4) + rb + r;
        const int g = g0 + (row >> 5) * 63 + (row & 31);
        const float cn = sigf(acc[mt][0][r] + bi) * tanhfast(acc[mt][2][r] + bu);
        const float hn = sigf(acc[mt][1][r] + bo) * tanhfast(cn);
        hout[(size_t)g * 128 + hcol] = hn;
        hstash[row * 128 + hcol] = f2bf(hn);
        cstash[row * 128 + hcol] = cn;
      }
    }
  }
  __syncthreads();   // stash visible; Alds free for reuse

  // ---- Phase 1 staging: 32 lvl1 rows, K=512 fragment image (NKS=16) ----
  // emb part (k<256)
#pragma unroll
  for (int c = 0; c < 2; ++c) {
    const int ks_e = tid >> 6;
    const int lq = tid & 63;
    const int k0 = ks_e * 32 + (lq >> 4) * 8;
    const int rblk = c * 16 + (lq & 15);
    const int g = g0 + (rblk >> 4) * 63 + 32 + (rblk & 15);
    const float4 v0 = *(const float4*)&emb[(size_t)g * 256 + k0];
    const float4 v1 = *(const float4*)&emb[(size_t)g * 256 + k0 + 4];
    ushort4 p0, p1;
    p0.x = f2bf(v0.x); p0.y = f2bf(v0.y); p0.z = f2bf(v0.z); p0.w = f2bf(v0.w);
    p1.x = f2bf(v1.x); p1.y = f2bf(v1.y); p1.z = f2bf(v1.z); p1.w = f2bf(v1.w);
    unsigned short* dst = &Alds[((c * 16 + ks_e) * 64 + lq) * 8];
    *(ushort4*)dst = p0;
    *(ushort4*)(dst + 4) = p1;
  }
  // ht part (k 256..511) from hstash: 16 threads/row, 8 cols each
  {
    const int rblk = tid >> 4, q = tid & 15;
    const int i = rblk >> 4, j = rblk & 15;
    const int gp = g0 + i * 63 + 32 + j;
    const int ch0 = i * 32 + 2 * j, ch1 = ch0 + 1;     // leaf stash rows
    const int ty0 = ctype[2 * gp], ty1 = ctype[2 * gp + 1];
    const float c0 = cmask[2 * gp], c1 = cmask[2 * gp + 1];
    const float w00 = (ty0 == 0) ? c0 : 0.f, w01 = (ty1 == 0) ? c1 : 0.f;
    const float w10 = (ty0 == 1) ? c0 : 0.f, w11 = (ty1 == 1) ? c1 : 0.f;
    const int jc = q * 8;
    const u16x8 va = *(const u16x8*)&hstash[ch0 * 128 + jc];
    const u16x8 vb = *(const u16x8*)&hstash[ch1 * 128 + jc];
    u16x8 o0, o1;
#pragma unroll
    for (int e = 0; e < 8; ++e) {
      const float fa = bf2f(va[e]), fb = bf2f(vb[e]);
      o0[e] = f2bf(w00 * fa + w01 * fb);
      o1[e] = f2bf(w10 * fa + w11 * fb);
    }
    *(u16x8*)&Alds[a_addr<16>(rblk, 256 + jc)] = o0;
    *(u16x8*)&Alds[a_addr<16>(rblk, 384 + jc)] = o1;
  }
  __syncthreads();

  // ---- Phase 1 GEMM: MT=2, NT=5, slices 0..15 ----
  {
    f32x4 acc[2][5];
#pragma unroll
    for (int mt = 0; mt < 2; ++mt)
#pragma unroll
      for (int t = 0; t < 5; ++t) acc[mt][t] = (f32x4){0.f, 0.f, 0.f, 0.f};
    bf16x8 bA[5], bB[5];
#pragma unroll
    for (int t = 0; t < 5; ++t) bA[t] = *(const bf16x8*)&Bw[(size_t)t * 65536];
#pragma unroll
    for (int ks2 = 0; ks2 < 8; ++ks2) {
#pragma unroll
      for (int half = 0; half < 2; ++half) {
        const int ks = 2 * ks2 + half;
        bf16x8* cur = half ? bB : bA;
        bf16x8* nxt = half ? bA : bB;
        if (ks + 1 < 16) {
#pragma unroll
          for (int t = 0; t < 5; ++t)
            nxt[t] = *(const bf16x8*)&Bw[(size_t)t * 65536 + (ks + 1) * 512];
        }
        __builtin_amdgcn_s_setprio(1);
#pragma unroll
        for (int mt = 0; mt < 2; ++mt) {
          const bf16x8 a = *(const bf16x8*)&Alds[((mt * 16 + ks) * 64 + lane) << 3];
#pragma unroll
          for (int t = 0; t < 5; ++t)
            acc[mt][t] = __builtin_amdgcn_mfma_f32_16x16x32_bf16(a, cur[t], acc[mt][t], 0, 0, 0);
        }
        __builtin_amdgcn_s_setprio(0);
      }
    }
    // ---- Phase 1 epilogue: full LSTM with stash c; h,c -> HBM ----
    const float bi = b_iou[hcol], bo = b_iou[128 + hcol], bu = b_iou[256 + hcol];
    const float f0b = ufb[hcol], f1b = ufb[128 + hcol], bfv = bf_[hcol];
#pragma unroll
    for (int mt = 0; mt < 2; ++mt) {
#pragma unroll
      for (int r = 0; r < 4; ++r) {
        const int row = (mt << 4) + rb + r;
        const int i = row >> 4, j = row & 15;
        const int g = g0 + i * 63 + 32 + j;
        const int ch0 = i * 32 + 2 * j, ch1 = ch0 + 1;
        const int ty0 = ctype[2 * g], ty1 = ctype[2 * g + 1];
        const float c0v = cmask[2 * g], c1v = cmask[2 * g + 1];
        const float iv = acc[mt][0][r] + bi;
        const float ov = acc[mt][1][r] + bo;
        const float uv = acc[mt][2][r] + bu;
        const float f0 = acc[mt][3][r] + f0b;
        const float f1 = acc[mt][4][r] + f1b;
        const float fa = (ty0 == 0) ? f0 : f1;
        const float fb = (ty1 == 0) ? f0 : f1;
        const float ft0 = sigf(fa + bfv);
        const float ft1 = sigf(fb + bfv);
        const float ccell = ft0 * cstash[ch0 * 128 + hcol] * c0v +
                            ft1 * cstash[ch1 * 128 + hcol] * c1v;
        const float cn = sigf(iv) * tanhfast(uv) + ccell;
        const float hn = sigf(ov) * tanhfast(cn);
        cbuf[(size_t)g * 128 + hcol] = cn;
        hout[(size_t)g * 128 + hcol] = hn;
      }
    }
  }
}

// ======================= tail levels (R12 verbatim) ========================
template <bool LEAF, int MT, int WPE>
__global__ __launch_bounds__(512, WPE) void lvl_kernel(
    const float* __restrict__ emb, const float* __restrict__ cmask,
    const int* __restrict__ cidx, const int* __restrict__ ctype,
    const unsigned short* __restrict__ BTf,
    const float* __restrict__ b_iou, const float* __restrict__ ufb,
    const float* __restrict__ bf_,
    float* __restrict__ hout, float* __restrict__ cbuf,
    int lc, int cntm1, int offs) {
  constexpr int KD = LEAF ? 256 : 512;
  constexpr int NKS = KD / 32;
  constexpr int NT = LEAF ? 3 : 5;
  constexpr int ROWS = MT * 16;
  __shared__ unsigned short Alds[ROWS * KD];

  const int tid = threadIdx.x;
  const int lane = tid & 63;
  const int w = tid >> 6;
  const int m0 = blockIdx.x * ROWS;

#pragma unroll
  for (int c = 0; c < MT; ++c) {
    const int ks_e = tid >> 6;
    const int lq = tid & 63;
    const int k0 = ks_e * 32 + (lq >> 4) * 8;
    const int rblk = c * 16 + (lq & 15);
    const int m = m0 + rblk;
    const int g = ((m >> lc) * 63) + offs + (m & cntm1);
    const float4 v0 = *(const float4*)&emb[(size_t)g * 256 + k0];
    const float4 v1 = *(const float4*)&emb[(size_t)g * 256 + k0 + 4];
    ushort4 p0, p1;
    p0.x = f2bf(v0.x); p0.y = f2bf(v0.y); p0.z = f2bf(v0.z); p0.w = f2bf(v0.w);
    p1.x = f2bf(v1.x); p1.y = f2bf(v1.y); p1.z = f2bf(v1.z); p1.w = f2bf(v1.w);
    unsigned short* dst = &Alds[((c * NKS + ks_e) * 64 + lq) * 8];
    *(ushort4*)dst = p0;
    *(ushort4*)(dst + 4) = p1;
  }

  if (!LEAF) {
    constexpr int TPR = 512 / ROWS;
    constexpr int CPT = 128 / TPR;
    const int rblk = tid / TPR, q = tid % TPR;
    const int m = m0 + rblk;
    const int g = ((m >> lc) * 63) + offs + (m & cntm1);
    const int ch0 = cidx[2 * g], ch1 = cidx[2 * g + 1];
    const int ty0 = ctype[2 * g], ty1 = ctype[2 * g + 1];
    const float c0 = cmask[2 * g], c1 = cmask[2 * g + 1];
    const float w00 = (ty0 == 0) ? c0 : 0.f, w01 = (ty1 == 0) ? c1 : 0.f;
    const float w10 = (ty0 == 1) ? c0 : 0.f, w11 = (ty1 == 1) ? c1 : 0.f;
#pragma unroll
    for (int jj = 0; jj < CPT / 4; ++jj) {
      const int j = q * CPT + jj * 4;
      float4 a = *(const float4*)&hout[(size_t)ch0 * 128 + j];
      float4 b = *(const float4*)&hout[(size_t)ch1 * 128 + j];
      ushort4 p0, p1;
      p0.x = f2bf(w00 * a.x + w01 * b.x);
      p0.y = f2bf(w00 * a.y + w01 * b.y);
      p0.z = f2bf(w00 * a.z + w01 * b.z);
      p0.w = f2bf(w00 * a.w + w01 * b.w);
      p1.x = f2bf(w10 * a.x + w11 * b.x);
      p1.y = f2bf(w10 * a.y + w11 * b.y);
      p1.z = f2bf(w10 * a.z + w11 * b.z);
      p1.w = f2bf(w10 * a.w + w11 * b.w);
      *(ushort4*)&Alds[a_addr<NKS>(rblk, 256 + j)] = p0;
      *(ushort4*)&Alds[a_addr<NKS>(rblk, 384 + j)] = p1;
    }
  }
  __syncthreads();

  f32x4 acc[MT][NT];
#pragma unroll
  for (int mt = 0; mt < MT; ++mt)
#pragma unroll
    for (int t = 0; t < NT; ++t) acc[mt][t] = (f32x4){0.f, 0.f, 0.f, 0.f};

  const unsigned short* Bw = BTf + (size_t)w * 8192 + lane * 8;
  bf16x8 bA[NT], bB[NT];
#pragma unroll
  for (int t = 0; t < NT; ++t)
    bA[t] = *(const bf16x8*)&Bw[(size_t)t * 65536];

  auto step = [&](bf16x8(&cur)[NT], bf16x8(&nxt)[NT], int ks) {
    if (ks + 1 < NKS) {
#pragma unroll
      for (int t = 0; t < NT; ++t)
        nxt[t] = *(const bf16x8*)&Bw[(size_t)t * 65536 + (ks + 1) * 512];
    }
    __builtin_amdgcn_s_setprio(1);
#pragma unroll
    for (int mt = 0; mt < MT; ++mt) {
      const bf16x8 a = *(const bf16x8*)&Alds[((mt * NKS + ks) * 64 + lane) << 3];
#pragma unroll
      for (int t = 0; t < NT; ++t)
        acc[mt][t] = __builtin_amdgcn_mfma_f32_16x16x32_bf16(a, cur[t], acc[mt][t], 0, 0, 0);
    }
    __builtin_amdgcn_s_setprio(0);
  };
#pragma unroll
  for (int ks2 = 0; ks2 < NKS / 2; ++ks2) {
    step(bA, bB, 2 * ks2);
    step(bB, bA, 2 * ks2 + 1);
  }

  const int cl = lane & 15;
  const int rb = (lane >> 4) << 2;
  const int hcol = w * 16 + cl;
  const float bi = b_iou[hcol];
  const float bo = b_iou[128 + hcol];
  const float bu = b_iou[256 + hcol];
  float f0b = 0.f, f1b = 0.f, bfv = 0.f;
  if (!LEAF) { f0b = ufb[hcol]; f1b = ufb[128 + hcol]; bfv = bf_[hcol]; }

#pragma unroll
  for (int mt = 0; mt < MT; ++mt) {
#pragma unroll
    for (int r = 0; r < 4; ++r) {
      const int m = m0 + (mt << 4) + rb + r;
      const int g = ((m >> lc) * 63) + offs + (m & cntm1);
      const float iv = acc[mt][0][r] + bi;
      const float ov = acc[mt][1][r] + bo;
      const float uv = acc[mt][2][r] + bu;
      float cn;
      if (LEAF) {
        cn = sigf(iv) * tanhfast(uv);
      } else {
        const int ch0 = cidx[2 * g], ch1 = cidx[2 * g + 1];
        const int ty0 = ctype[2 * g], ty1 = ctype[2 * g + 1];
        const float c0v = cmask[2 * g], c1v = cmask[2 * g + 1];
        const float f0 = acc[mt][3][r] + f0b;
        const float f1 = acc[mt][4][r] + f1b;
        const float fa = (ty0 == 0) ? f0 : f1;
        const float fb = (ty1 == 0) ? f0 : f1;
        const float ft0 = sigf(fa + bfv);
        const float ft1 = sigf(fb + bfv);
        const float ccell = ft0 * cbuf[(size_t)ch0 * 128 + hcol] * c0v +
                            ft1 * cbuf[(size_t)ch1 * 128 + hcol] * c1v;
        cn = sigf(iv) * tanhfast(uv) + ccell;
      }
      const float hn = sigf(ov) * tanhfast(cn);
      cbuf[(size_t)g * 128 + hcol] = cn;
      hout[(size_t)g * 128 + hcol] = hn;
    }
  }
}

extern "C" void kernel_launch(void* const* d_in, const int* in_sizes, int n_in,
                              void* d_out, int out_size, void* d_ws, size_t ws_size,
                              hipStream_t stream) {
  (void)in_sizes; (void)n_in; (void)out_size; (void)ws_size;
  const float* emb   = (const float*)d_in[0];
  const float* cmask = (const float*)d_in[1];
  const float* W_iou = (const float*)d_in[2];
  const float* U_iou = (const float*)d_in[3];
  const float* b_iou = (const float*)d_in[4];
  const float* W_f   = (const float*)d_in[5];
  const float* U_f_w = (const float*)d_in[6];
  const float* U_f_b = (const float*)d_in[7];
  const float* b_f   = (const float*)d_in[8];
  const int* cidx    = (const int*)d_in[9];
  const int* ctype   = (const int*)d_in[10];
  float* hout = (float*)d_out;

  unsigned short* BTf = (unsigned short*)d_ws;                // 655360 B
  float* cbuf = (float*)((char*)d_ws + (size_t)(1 << 20));    // N*128*4 = 132 MB

  prep_kernel<<<1280, 256, 0, stream>>>(W_iou, U_iou, W_f, U_f_w, BTf);

  // leaf + lvl1 fused: 2 trees per block
  fused_kernel<<<2048, 512, 0, stream>>>(emb, cmask, ctype, BTf, b_iou,
                                         U_f_b, b_f, hout, cbuf);
  // levels 2..5 (R12 tails)
  lvl_kernel<false, 2, 4><<<1024, 512, 0, stream>>>(emb, cmask, cidx, ctype, BTf, b_iou,
                                                    U_f_b, b_f, hout, cbuf, 3, 7, 48);
  lvl_kernel<false, 2, 4><<<512, 512, 0, stream>>>(emb, cmask, cidx, ctype, BTf, b_iou,
                                                   U_f_b, b_f, hout, cbuf, 2, 3, 56);
  lvl_kernel<false, 1, 4><<<512, 512, 0, stream>>>(emb, cmask, cidx, ctype, BTf, b_iou,
                                                   U_f_b, b_f, hout, cbuf, 1, 1, 60);
  lvl_kernel<false, 1, 4><<<256, 512, 0, stream>>>(emb, cmask, cidx, ctype, BTf, b_iou,
                                                   U_f_b, b_f, hout, cbuf, 0, 0, 62);
}